// Round 1
// baseline (1331.111 us; speedup 1.0000x reference)
//
#include <hip/hip_runtime.h>

#define B_  2
#define N_  2048
#define C_  1024
#define H_  16
#define HD_ 64
#define QSZ (B_*H_*N_*HD_)   // 4194304 floats per q/k/v buffer

// ---------------------------------------------------------------------------
// Kernel 1: qkv = x @ W_qkv  (M=4096, K=1024, N=3072), scatter into
// q/k/v buffers in [B,H,N,hd] layout.
// Tiled 64x64, BK=16, 256 threads, 4x4 micro-tile per thread.
// ---------------------------------------------------------------------------
__global__ __launch_bounds__(256) void gemm_qkv_kernel(
    const float* __restrict__ X,     // [4096,1024]
    const float* __restrict__ W,     // [1024,3072]
    float* __restrict__ qb, float* __restrict__ kb, float* __restrict__ vb)
{
    __shared__ float As[16][68];   // [kk][m]
    __shared__ float Bs[16][68];   // [kk][n]
    const int t  = threadIdx.x;
    const int tx = t & 15, ty = t >> 4;
    const int row0 = blockIdx.y * 64;
    const int col0 = blockIdx.x * 64;
    const int ar  = t >> 2, akv = (t & 3) * 4;   // A-tile: row, k-offset
    const int bk  = t >> 4, bnv = (t & 15) * 4;  // B-tile: k-row, n-offset
    float acc[4][4] = {};
    for (int k0 = 0; k0 < 1024; k0 += 16) {
        float4 a = *(const float4*)&X[(row0 + ar) * 1024 + k0 + akv];
        float4 b = *(const float4*)&W[(size_t)(k0 + bk) * 3072 + col0 + bnv];
        As[akv + 0][ar] = a.x; As[akv + 1][ar] = a.y;
        As[akv + 2][ar] = a.z; As[akv + 3][ar] = a.w;
        *(float4*)&Bs[bk][bnv] = b;
        __syncthreads();
        #pragma unroll
        for (int kk = 0; kk < 16; ++kk) {
            float4 av = *(float4*)&As[kk][ty * 4];
            float4 bv = *(float4*)&Bs[kk][tx * 4];
            const float aa[4] = {av.x, av.y, av.z, av.w};
            const float bb[4] = {bv.x, bv.y, bv.z, bv.w};
            #pragma unroll
            for (int i = 0; i < 4; ++i)
                #pragma unroll
                for (int j = 0; j < 4; ++j)
                    acc[i][j] += aa[i] * bb[j];
        }
        __syncthreads();
    }
    // epilogue: scatter into q/k/v [B,H,N,hd]
    const int gcol0 = col0 + tx * 4;
    const int which = gcol0 >> 10;
    const int rem   = gcol0 & 1023;
    const int h     = rem >> 6;
    const int d     = rem & 63;
    float* dstbuf = (which == 0) ? qb : (which == 1) ? kb : vb;
    #pragma unroll
    for (int i = 0; i < 4; ++i) {
        const int grow = row0 + ty * 4 + i;     // 0..4095 = b*2048+n
        const int bidx = grow >> 11;
        const int n    = grow & 2047;
        float4 v4 = {acc[i][0], acc[i][1], acc[i][2], acc[i][3]};
        *(float4*)&dstbuf[(((size_t)(bidx * H_ + h) * N_ + n) * HD_) + d] = v4;
    }
}

// ---------------------------------------------------------------------------
// Kernel 2: LayerNorm over hd=64 for q and k (in place), q *= hd^-0.5.
// One wave (64 lanes) per row; 4 rows per 256-thread block.
// grid = (BHN/4, 2)  y==0 -> q, y==1 -> k
// ---------------------------------------------------------------------------
__global__ __launch_bounds__(256) void ln_kernel(
    float* __restrict__ qb, float* __restrict__ kb,
    const float* __restrict__ qw, const float* __restrict__ qbi,
    const float* __restrict__ kw, const float* __restrict__ kbi)
{
    const int lane = threadIdx.x & 63;
    const int w    = threadIdx.x >> 6;
    const int row  = blockIdx.x * 4 + w;
    const bool isq = (blockIdx.y == 0);
    float* p = (isq ? qb : kb) + (size_t)row * 64 + lane;
    const float* wt = isq ? qw : kw;
    const float* bi = isq ? qbi : kbi;
    float v = *p;
    float s = v;
    #pragma unroll
    for (int o = 1; o < 64; o <<= 1) s += __shfl_xor(s, o);
    const float mu = s * (1.0f / 64.0f);
    const float d  = v - mu;
    float s2 = d * d;
    #pragma unroll
    for (int o = 1; o < 64; o <<= 1) s2 += __shfl_xor(s2, o);
    const float var = s2 * (1.0f / 64.0f);
    float y = d * rsqrtf(var + 1e-5f) * wt[lane] + bi[lane];
    if (isq) y *= 0.125f;   // hd^-0.5 folded into q
    *p = y;
}

// ---------------------------------------------------------------------------
// Kernel 3: flash attention. One block per (b*H+h, 64-row Q tile).
// K/V tiles of 32 rows. fp32, online softmax. Writes o in [B,N,C] layout.
// ---------------------------------------------------------------------------
__global__ __launch_bounds__(256) void flash_kernel(
    const float* __restrict__ qb, const float* __restrict__ kb,
    const float* __restrict__ vb, float* __restrict__ ob)
{
    __shared__ float Qs[64][68];
    __shared__ float Ks[32][68];
    __shared__ float Vs[32][68];
    __shared__ float Ps[64][36];
    const int t  = threadIdx.x;
    const int tx = t & 15, ty = t >> 4;
    const int q0 = blockIdx.x * 64;
    const int bh = blockIdx.y;                       // b*H + h
    const float* Q = qb + (size_t)bh * N_ * HD_;
    const float* K = kb + (size_t)bh * N_ * HD_;
    const float* V = vb + (size_t)bh * N_ * HD_;
    // load Q tile (64 rows x 64 floats)
    #pragma unroll
    for (int rep = 0; rep < 4; ++rep) {
        int idx = t + rep * 256;
        int r = idx >> 4, dv = (idx & 15) * 4;
        *(float4*)&Qs[r][dv] = *(const float4*)&Q[(size_t)(q0 + r) * 64 + dv];
    }
    float m_i[4], l_i[4], acc[4][4];
    #pragma unroll
    for (int i = 0; i < 4; ++i) {
        m_i[i] = -1e30f; l_i[i] = 0.0f;
        #pragma unroll
        for (int j = 0; j < 4; ++j) acc[i][j] = 0.0f;
    }
    for (int kt = 0; kt < N_; kt += 32) {
        __syncthreads();   // prior reads of Ks/Vs/Ps done; Qs ready on iter 0
        #pragma unroll
        for (int rep = 0; rep < 2; ++rep) {
            int idx = t + rep * 256;
            int r = idx >> 4, dv = (idx & 15) * 4;
            *(float4*)&Ks[r][dv] = *(const float4*)&K[(size_t)(kt + r) * 64 + dv];
            *(float4*)&Vs[r][dv] = *(const float4*)&V[(size_t)(kt + r) * 64 + dv];
        }
        __syncthreads();
        // S[r][c] = q_r . k_c ; rows 4ty+i, cols 2tx+j
        float s[4][2] = {};
        for (int d0 = 0; d0 < 64; d0 += 4) {
            float4 qv[4], kv[2];
            #pragma unroll
            for (int i = 0; i < 4; ++i) qv[i] = *(float4*)&Qs[4 * ty + i][d0];
            #pragma unroll
            for (int j = 0; j < 2; ++j) kv[j] = *(float4*)&Ks[2 * tx + j][d0];
            #pragma unroll
            for (int i = 0; i < 4; ++i)
                #pragma unroll
                for (int j = 0; j < 2; ++j)
                    s[i][j] += qv[i].x * kv[j].x + qv[i].y * kv[j].y +
                               qv[i].z * kv[j].z + qv[i].w * kv[j].w;
        }
        // online softmax per row (reduce across 16 lanes sharing ty)
        float alpha[4];
        #pragma unroll
        for (int i = 0; i < 4; ++i) {
            float mx = fmaxf(s[i][0], s[i][1]);
            #pragma unroll
            for (int o = 1; o < 16; o <<= 1) mx = fmaxf(mx, __shfl_xor(mx, o));
            const float m_new = fmaxf(m_i[i], mx);
            const float p0 = __expf(s[i][0] - m_new);
            const float p1 = __expf(s[i][1] - m_new);
            float sum = p0 + p1;
            #pragma unroll
            for (int o = 1; o < 16; o <<= 1) sum += __shfl_xor(sum, o);
            alpha[i] = __expf(m_i[i] - m_new);
            l_i[i] = l_i[i] * alpha[i] + sum;
            m_i[i] = m_new;
            Ps[4 * ty + i][2 * tx + 0] = p0;
            Ps[4 * ty + i][2 * tx + 1] = p1;
        }
        #pragma unroll
        for (int i = 0; i < 4; ++i)
            #pragma unroll
            for (int j = 0; j < 4; ++j) acc[i][j] *= alpha[i];
        __syncthreads();
        // acc += P @ V  (cols 4tx+j over hd)
        for (int c0 = 0; c0 < 32; c0 += 4) {
            float4 pv[4];
            #pragma unroll
            for (int i = 0; i < 4; ++i) pv[i] = *(float4*)&Ps[4 * ty + i][c0];
            const float* pf = (const float*)pv;   // pf[i*4+cc]
            #pragma unroll
            for (int cc = 0; cc < 4; ++cc) {
                float4 vv = *(float4*)&Vs[c0 + cc][4 * tx];
                #pragma unroll
                for (int i = 0; i < 4; ++i) {
                    const float p = pf[i * 4 + cc];
                    acc[i][0] += p * vv.x; acc[i][1] += p * vv.y;
                    acc[i][2] += p * vv.z; acc[i][3] += p * vv.w;
                }
            }
        }
    }
    // write o in [B,N,C] layout
    const int bidx = bh >> 4, h = bh & 15;
    #pragma unroll
    for (int i = 0; i < 4; ++i) {
        const int n = q0 + 4 * ty + i;
        const float inv = 1.0f / l_i[i];
        float4 o4 = {acc[i][0] * inv, acc[i][1] * inv,
                     acc[i][2] * inv, acc[i][3] * inv};
        *(float4*)&ob[((size_t)(bidx * N_ + n) * C_) + h * 64 + 4 * tx] = o4;
    }
}

// ---------------------------------------------------------------------------
// Kernel 4: out = o @ W_proj + b_proj  (M=4096, K=1024, N=1024)
// ---------------------------------------------------------------------------
__global__ __launch_bounds__(256) void gemm_proj_kernel(
    const float* __restrict__ O,     // [4096,1024]
    const float* __restrict__ W,     // [1024,1024]
    const float* __restrict__ bias,  // [1024]
    float* __restrict__ out)         // [4096,1024]
{
    __shared__ float As[16][68];
    __shared__ float Bs[16][68];
    const int t  = threadIdx.x;
    const int tx = t & 15, ty = t >> 4;
    const int row0 = blockIdx.y * 64;
    const int col0 = blockIdx.x * 64;
    const int ar  = t >> 2, akv = (t & 3) * 4;
    const int bk  = t >> 4, bnv = (t & 15) * 4;
    float acc[4][4] = {};
    for (int k0 = 0; k0 < 1024; k0 += 16) {
        float4 a = *(const float4*)&O[(size_t)(row0 + ar) * 1024 + k0 + akv];
        float4 b = *(const float4*)&W[(size_t)(k0 + bk) * 1024 + col0 + bnv];
        As[akv + 0][ar] = a.x; As[akv + 1][ar] = a.y;
        As[akv + 2][ar] = a.z; As[akv + 3][ar] = a.w;
        *(float4*)&Bs[bk][bnv] = b;
        __syncthreads();
        #pragma unroll
        for (int kk = 0; kk < 16; ++kk) {
            float4 av = *(float4*)&As[kk][ty * 4];
            float4 bv = *(float4*)&Bs[kk][tx * 4];
            const float aa[4] = {av.x, av.y, av.z, av.w};
            const float bb[4] = {bv.x, bv.y, bv.z, bv.w};
            #pragma unroll
            for (int i = 0; i < 4; ++i)
                #pragma unroll
                for (int j = 0; j < 4; ++j)
                    acc[i][j] += aa[i] * bb[j];
        }
        __syncthreads();
    }
    const int gcol0 = col0 + tx * 4;
    float4 b4 = *(const float4*)&bias[gcol0];
    #pragma unroll
    for (int i = 0; i < 4; ++i) {
        const int grow = row0 + ty * 4 + i;
        float4 v4 = {acc[i][0] + b4.x, acc[i][1] + b4.y,
                     acc[i][2] + b4.z, acc[i][3] + b4.w};
        *(float4*)&out[(size_t)grow * 1024 + gcol0] = v4;
    }
}

// ---------------------------------------------------------------------------
extern "C" void kernel_launch(void* const* d_in, const int* in_sizes, int n_in,
                              void* d_out, int out_size, void* d_ws, size_t ws_size,
                              hipStream_t stream) {
    const float* x      = (const float*)d_in[0];
    const float* W_qkv  = (const float*)d_in[1];
    const float* qn_w   = (const float*)d_in[2];
    const float* qn_b   = (const float*)d_in[3];
    const float* kn_w   = (const float*)d_in[4];
    const float* kn_b   = (const float*)d_in[5];
    const float* W_proj = (const float*)d_in[6];
    const float* b_proj = (const float*)d_in[7];
    float* out = (float*)d_out;

    float* ws = (float*)d_ws;
    float* qb = ws;
    float* kb = ws + (size_t)QSZ;
    float* vb = ws + (size_t)2 * QSZ;
    float* ob = ws + (size_t)3 * QSZ;   // [B,N,C]

    // 1) qkv GEMM, scatter into q/k/v [B,H,N,hd]
    gemm_qkv_kernel<<<dim3(48, 64), 256, 0, stream>>>(x, W_qkv, qb, kb, vb);
    // 2) LayerNorm q,k (in place), q scaled by hd^-0.5
    ln_kernel<<<dim3((B_ * H_ * N_) / 4, 2), 256, 0, stream>>>(qb, kb, qn_w, qn_b, kn_w, kn_b);
    // 3) flash attention -> o [B,N,C]
    flash_kernel<<<dim3(N_ / 64, B_ * H_), 256, 0, stream>>>(qb, kb, vb, ob);
    // 4) output projection + bias
    gemm_proj_kernel<<<dim3(16, 64), 256, 0, stream>>>(ob, W_proj, b_proj, out);
}

// Round 2
// 684.585 us; speedup vs baseline: 1.9444x; 1.9444x over previous
//
#include <hip/hip_runtime.h>
#include <hip/hip_bf16.h>

#define B_  2
#define N_  2048
#define C_  1024
#define H_  16
#define HD_ 64
#define QSZ (B_*H_*N_*HD_)   // elements per q/k/v buffer

typedef __attribute__((ext_vector_type(8))) short short8;   // 8 bf16 = 4 VGPRs
typedef __attribute__((ext_vector_type(4))) float floatx4;

__device__ __forceinline__ unsigned short f2bf(float f) {
    unsigned int u = __builtin_bit_cast(unsigned int, f);
    u += 0x7fff + ((u >> 16) & 1);          // round-to-nearest-even
    return (unsigned short)(u >> 16);
}
__device__ __forceinline__ float bf2f(unsigned short h) {
    return __builtin_bit_cast(float, (unsigned int)h << 16);
}

// ---------------------------------------------------------------------------
// Kernel 1: qkv = x @ W_qkv  (M=4096, K=1024, N=3072) fp32 compute,
// epilogue converts to bf16 and scatters into q/k/v [B,H,N,hd].
// ---------------------------------------------------------------------------
__global__ __launch_bounds__(256) void gemm_qkv_kernel(
    const float* __restrict__ X, const float* __restrict__ W,
    unsigned short* __restrict__ qb, unsigned short* __restrict__ kb,
    unsigned short* __restrict__ vb)
{
    __shared__ float As[16][68];
    __shared__ float Bs[16][68];
    const int t  = threadIdx.x;
    const int tx = t & 15, ty = t >> 4;
    const int row0 = blockIdx.y * 64;
    const int col0 = blockIdx.x * 64;
    const int ar  = t >> 2, akv = (t & 3) * 4;
    const int bk  = t >> 4, bnv = (t & 15) * 4;
    float acc[4][4] = {};
    for (int k0 = 0; k0 < 1024; k0 += 16) {
        float4 a = *(const float4*)&X[(row0 + ar) * 1024 + k0 + akv];
        float4 b = *(const float4*)&W[(size_t)(k0 + bk) * 3072 + col0 + bnv];
        As[akv + 0][ar] = a.x; As[akv + 1][ar] = a.y;
        As[akv + 2][ar] = a.z; As[akv + 3][ar] = a.w;
        *(float4*)&Bs[bk][bnv] = b;
        __syncthreads();
        #pragma unroll
        for (int kk = 0; kk < 16; ++kk) {
            float4 av = *(float4*)&As[kk][ty * 4];
            float4 bv = *(float4*)&Bs[kk][tx * 4];
            const float aa[4] = {av.x, av.y, av.z, av.w};
            const float bb[4] = {bv.x, bv.y, bv.z, bv.w};
            #pragma unroll
            for (int i = 0; i < 4; ++i)
                #pragma unroll
                for (int j = 0; j < 4; ++j)
                    acc[i][j] += aa[i] * bb[j];
        }
        __syncthreads();
    }
    const int gcol0 = col0 + tx * 4;
    const int which = gcol0 >> 10;
    const int rem   = gcol0 & 1023;
    const int h     = rem >> 6;
    const int d     = rem & 63;
    unsigned short* dstbuf = (which == 0) ? qb : (which == 1) ? kb : vb;
    #pragma unroll
    for (int i = 0; i < 4; ++i) {
        const int grow = row0 + ty * 4 + i;
        const int bidx = grow >> 11;
        const int n    = grow & 2047;
        ushort4 u4 = {f2bf(acc[i][0]), f2bf(acc[i][1]),
                      f2bf(acc[i][2]), f2bf(acc[i][3])};
        *(ushort4*)&dstbuf[(((size_t)(bidx * H_ + h) * N_ + n) * HD_) + d] = u4;
    }
}

// ---------------------------------------------------------------------------
// Kernel 2: LayerNorm over hd=64 for q and k (bf16 in/out, fp32 math).
// q scaled by hd^-0.5 (0.125 — exact in bf16).
// ---------------------------------------------------------------------------
__global__ __launch_bounds__(256) void ln_kernel(
    unsigned short* __restrict__ qb, unsigned short* __restrict__ kb,
    const float* __restrict__ qw, const float* __restrict__ qbi,
    const float* __restrict__ kw, const float* __restrict__ kbi)
{
    const int lane = threadIdx.x & 63;
    const int w    = threadIdx.x >> 6;
    const int row  = blockIdx.x * 4 + w;
    const bool isq = (blockIdx.y == 0);
    unsigned short* p = (isq ? qb : kb) + (size_t)row * 64 + lane;
    const float* wt = isq ? qw : kw;
    const float* bi = isq ? qbi : kbi;
    float v = bf2f(*p);
    float s = v;
    #pragma unroll
    for (int o = 1; o < 64; o <<= 1) s += __shfl_xor(s, o);
    const float mu = s * (1.0f / 64.0f);
    const float d  = v - mu;
    float s2 = d * d;
    #pragma unroll
    for (int o = 1; o < 64; o <<= 1) s2 += __shfl_xor(s2, o);
    const float var = s2 * (1.0f / 64.0f);
    float y = d * rsqrtf(var + 1e-5f) * wt[lane] + bi[lane];
    if (isq) y *= 0.125f;
    *p = f2bf(y);
}

// ---------------------------------------------------------------------------
// Kernel 3: flash attention, bf16 MFMA (16x16x32).
// Block = 256 threads = 4 waves; Q tile 64 rows (16/wave); kv tile 64.
// LDS rows padded to 72 bf16 (144 B, 16B-aligned, <=2-way conflicts on b128).
// Qs is reused as Ps (P round-trip) after Q fragments are cached in regs.
// ---------------------------------------------------------------------------
__global__ __launch_bounds__(256) void flash_kernel(
    const unsigned short* __restrict__ qb, const unsigned short* __restrict__ kb,
    const unsigned short* __restrict__ vb, float* __restrict__ ob)
{
    __shared__ __align__(16) unsigned short Ks[64][72];
    __shared__ __align__(16) unsigned short Vt[64][72];   // transposed: [d][kv]
    __shared__ __align__(16) unsigned short QPs[64][72];  // Q tile, then P
    const int t    = threadIdx.x;
    const int lane = t & 63;
    const int w    = t >> 6;
    const int l15  = lane & 15;
    const int quad = lane >> 4;
    const int q0   = blockIdx.x * 64;
    const int bh   = blockIdx.y;
    const unsigned short* Q = qb + (size_t)bh * N_ * HD_;
    const unsigned short* K = kb + (size_t)bh * N_ * HD_;
    const unsigned short* V = vb + (size_t)bh * N_ * HD_;

    // stage Q tile (64x64 bf16)
    {
        const int r = t >> 3, c0 = (t & 7) * 8;
        *(short8*)&QPs[r][c0]      = *(const short8*)&Q[(size_t)(q0 + r) * 64 + c0];
        *(short8*)&QPs[r + 32][c0] = *(const short8*)&Q[(size_t)(q0 + r + 32) * 64 + c0];
    }
    __syncthreads();
    // cache Q fragments: A[m=l15][k=quad*8+j], kk-step 0/1
    short8 qa0 = *(const short8*)&QPs[16 * w + l15][quad * 8];
    short8 qa1 = *(const short8*)&QPs[16 * w + l15][32 + quad * 8];
    // (every wave reads its frags before the first in-loop barrier, so the
    //  later reuse of QPs as Ps cannot race these reads)

    floatx4 acc[4] = {floatx4{0,0,0,0}, floatx4{0,0,0,0},
                      floatx4{0,0,0,0}, floatx4{0,0,0,0}};
    float m_i[4] = {-1e30f, -1e30f, -1e30f, -1e30f};
    float l_i[4] = {0.f, 0.f, 0.f, 0.f};

    for (int kt = 0; kt < N_; kt += 64) {
        __syncthreads();   // prior iteration's Ks/Vt reads complete
        // stage K tile (row-major) and V tile (transposed)
        {
            const int r = t >> 3, c0 = (t & 7) * 8;
            *(short8*)&Ks[r][c0]      = *(const short8*)&K[(size_t)(kt + r) * 64 + c0];
            *(short8*)&Ks[r + 32][c0] = *(const short8*)&K[(size_t)(kt + r + 32) * 64 + c0];
            const int vr = (t & 31) * 2, vc = (t >> 5) * 8;
            short8 v0 = *(const short8*)&V[(size_t)(kt + vr) * 64 + vc];
            short8 v1 = *(const short8*)&V[(size_t)(kt + vr + 1) * 64 + vc];
            #pragma unroll
            for (int j = 0; j < 8; ++j) {
                unsigned int pk = (unsigned short)v0[j] |
                                  ((unsigned int)(unsigned short)v1[j] << 16);
                *(unsigned int*)&Vt[vc + j][vr] = pk;
            }
        }
        __syncthreads();

        // S = Q . K^T : 4 col-tiles of 16, K-dim 64 = 2 MFMA steps
        floatx4 sc[4];
        #pragma unroll
        for (int ct = 0; ct < 4; ++ct) {
            short8 b0 = *(const short8*)&Ks[ct * 16 + l15][quad * 8];
            short8 b1 = *(const short8*)&Ks[ct * 16 + l15][32 + quad * 8];
            floatx4 r = {0.f, 0.f, 0.f, 0.f};
            r = __builtin_amdgcn_mfma_f32_16x16x32_bf16(qa0, b0, r, 0, 0, 0);
            r = __builtin_amdgcn_mfma_f32_16x16x32_bf16(qa1, b1, r, 0, 0, 0);
            sc[ct] = r;
        }

        // online softmax; rows r: row = quad*4+r, stats shared by 16 lanes
        float alpha[4];
        #pragma unroll
        for (int r = 0; r < 4; ++r) {
            float mx = fmaxf(fmaxf(sc[0][r], sc[1][r]), fmaxf(sc[2][r], sc[3][r]));
            #pragma unroll
            for (int o = 1; o < 16; o <<= 1) mx = fmaxf(mx, __shfl_xor(mx, o));
            const float m_new = fmaxf(m_i[r], mx);
            float p[4], sum = 0.f;
            #pragma unroll
            for (int ct = 0; ct < 4; ++ct) {
                p[ct] = __expf(sc[ct][r] - m_new);
                sum += p[ct];
            }
            #pragma unroll
            for (int o = 1; o < 16; o <<= 1) sum += __shfl_xor(sum, o);
            alpha[r] = __expf(m_i[r] - m_new);
            l_i[r] = l_i[r] * alpha[r] + sum;
            m_i[r] = m_new;
            const int prow = 16 * w + quad * 4 + r;
            #pragma unroll
            for (int ct = 0; ct < 4; ++ct)
                QPs[prow][ct * 16 + l15] = f2bf(p[ct]);
        }
        #pragma unroll
        for (int dt = 0; dt < 4; ++dt)
            #pragma unroll
            for (int r = 0; r < 4; ++r) acc[dt][r] *= alpha[r];

        // compiler-level fence: Ps writes above, A-frag reads below (same
        // wave's rows only; HW LDS ops are in-order per wave)
        asm volatile("" ::: "memory");

        // O += P . V : A-frag from Ps (own rows), B-frag from Vt (contig)
        #pragma unroll
        for (int kk = 0; kk < 2; ++kk) {
            short8 pa = *(const short8*)&QPs[16 * w + l15][kk * 32 + quad * 8];
            #pragma unroll
            for (int dt = 0; dt < 4; ++dt) {
                short8 vv = *(const short8*)&Vt[dt * 16 + l15][kk * 32 + quad * 8];
                acc[dt] = __builtin_amdgcn_mfma_f32_16x16x32_bf16(pa, vv, acc[dt], 0, 0, 0);
            }
        }
    }

    // write o [B,N,C] fp32
    const int bidx = bh >> 4, h = bh & 15;
    #pragma unroll
    for (int r = 0; r < 4; ++r) {
        const int n = q0 + 16 * w + quad * 4 + r;
        const float inv = 1.0f / l_i[r];
        #pragma unroll
        for (int dt = 0; dt < 4; ++dt)
            ob[((size_t)(bidx * N_ + n)) * C_ + h * 64 + dt * 16 + l15] = acc[dt][r] * inv;
    }
}

// ---------------------------------------------------------------------------
// Kernel 4: out = o @ W_proj + b_proj  (fp32)
// ---------------------------------------------------------------------------
__global__ __launch_bounds__(256) void gemm_proj_kernel(
    const float* __restrict__ O, const float* __restrict__ W,
    const float* __restrict__ bias, float* __restrict__ out)
{
    __shared__ float As[16][68];
    __shared__ float Bs[16][68];
    const int t  = threadIdx.x;
    const int tx = t & 15, ty = t >> 4;
    const int row0 = blockIdx.y * 64;
    const int col0 = blockIdx.x * 64;
    const int ar  = t >> 2, akv = (t & 3) * 4;
    const int bk  = t >> 4, bnv = (t & 15) * 4;
    float acc[4][4] = {};
    for (int k0 = 0; k0 < 1024; k0 += 16) {
        float4 a = *(const float4*)&O[(size_t)(row0 + ar) * 1024 + k0 + akv];
        float4 b = *(const float4*)&W[(size_t)(k0 + bk) * 1024 + col0 + bnv];
        As[akv + 0][ar] = a.x; As[akv + 1][ar] = a.y;
        As[akv + 2][ar] = a.z; As[akv + 3][ar] = a.w;
        *(float4*)&Bs[bk][bnv] = b;
        __syncthreads();
        #pragma unroll
        for (int kk = 0; kk < 16; ++kk) {
            float4 av = *(float4*)&As[kk][ty * 4];
            float4 bv = *(float4*)&Bs[kk][tx * 4];
            const float aa[4] = {av.x, av.y, av.z, av.w};
            const float bb[4] = {bv.x, bv.y, bv.z, bv.w};
            #pragma unroll
            for (int i = 0; i < 4; ++i)
                #pragma unroll
                for (int j = 0; j < 4; ++j)
                    acc[i][j] += aa[i] * bb[j];
        }
        __syncthreads();
    }
    const int gcol0 = col0 + tx * 4;
    float4 b4 = *(const float4*)&bias[gcol0];
    #pragma unroll
    for (int i = 0; i < 4; ++i) {
        const int grow = row0 + ty * 4 + i;
        float4 v4 = {acc[i][0] + b4.x, acc[i][1] + b4.y,
                     acc[i][2] + b4.z, acc[i][3] + b4.w};
        *(float4*)&out[(size_t)grow * 1024 + gcol0] = v4;
    }
}

// ---------------------------------------------------------------------------
extern "C" void kernel_launch(void* const* d_in, const int* in_sizes, int n_in,
                              void* d_out, int out_size, void* d_ws, size_t ws_size,
                              hipStream_t stream) {
    const float* x      = (const float*)d_in[0];
    const float* W_qkv  = (const float*)d_in[1];
    const float* qn_w   = (const float*)d_in[2];
    const float* qn_b   = (const float*)d_in[3];
    const float* kn_w   = (const float*)d_in[4];
    const float* kn_b   = (const float*)d_in[5];
    const float* W_proj = (const float*)d_in[6];
    const float* b_proj = (const float*)d_in[7];
    float* out = (float*)d_out;

    unsigned short* qb = (unsigned short*)d_ws;
    unsigned short* kb = qb + (size_t)QSZ;
    unsigned short* vb = kb + (size_t)QSZ;
    float* ob = (float*)(vb + (size_t)QSZ);   // [B,N,C] fp32

    gemm_qkv_kernel<<<dim3(48, 64), 256, 0, stream>>>(x, W_qkv, qb, kb, vb);
    ln_kernel<<<dim3((B_ * H_ * N_) / 4, 2), 256, 0, stream>>>(qb, kb, qn_w, qn_b, kn_w, kn_b);
    flash_kernel<<<dim3(N_ / 64, B_ * H_), 256, 0, stream>>>(qb, kb, vb, ob);
    gemm_proj_kernel<<<dim3(16, 64), 256, 0, stream>>>(ob, W_proj, b_proj, out);
}

// Round 3
// 288.606 us; speedup vs baseline: 4.6122x; 2.3720x over previous
//
#include <hip/hip_runtime.h>
#include <hip/hip_bf16.h>

#define B_  2
#define N_  2048
#define C_  1024
#define H_  16
#define HD_ 64
#define QSZ (B_*H_*N_*HD_)   // elements per q/k/v buffer

typedef __attribute__((ext_vector_type(8))) short short8;   // 8 bf16 = 4 VGPRs
typedef __attribute__((ext_vector_type(4))) float floatx4;

__device__ __forceinline__ unsigned short f2bf(float f) {
    unsigned int u = __builtin_bit_cast(unsigned int, f);
    u += 0x7fff + ((u >> 16) & 1);          // round-to-nearest-even
    return (unsigned short)(u >> 16);
}
__device__ __forceinline__ float bf2f(unsigned short h) {
    return __builtin_bit_cast(float, (unsigned int)h << 16);
}

// async global->LDS, 16 B per lane; LDS dest = wave-uniform base + lane*16
__device__ __forceinline__ void g2l16(const void* g, void* l) {
    __builtin_amdgcn_global_load_lds(
        (const __attribute__((address_space(1))) void*)g,
        (__attribute__((address_space(3))) void*)l, 16, 0, 0);
}

// ---------------------------------------------------------------------------
// pack fp32 -> bf16, same layout (for x and as a building block)
// ---------------------------------------------------------------------------
__global__ __launch_bounds__(256) void pack_bf16_kernel(
    const float* __restrict__ src, unsigned short* __restrict__ dst)
{
    const int i = blockIdx.x * 256 + threadIdx.x;
    float4 v = ((const float4*)src)[i];
    ushort4 o = {f2bf(v.x), f2bf(v.y), f2bf(v.z), f2bf(v.w)};
    ((ushort4*)dst)[i] = o;
}

// ---------------------------------------------------------------------------
// transpose + pack: W fp32 [Kd][Nd] -> Wt bf16 [Nd][Kd]; 32x32 LDS tiles
// grid = (Nd/32, Kd/32), 256 threads
// ---------------------------------------------------------------------------
__global__ __launch_bounds__(256) void transpose_pack_kernel(
    const float* __restrict__ W, unsigned short* __restrict__ Wt,
    int Kd, int Nd)
{
    __shared__ unsigned short tl[32][34];
    const int r  = threadIdx.x >> 3;
    const int c4 = (threadIdx.x & 7) * 4;
    const int n0 = blockIdx.x * 32, k0 = blockIdx.y * 32;
    float4 v = *(const float4*)&W[(size_t)(k0 + r) * Nd + n0 + c4];
    tl[r][c4 + 0] = f2bf(v.x); tl[r][c4 + 1] = f2bf(v.y);
    tl[r][c4 + 2] = f2bf(v.z); tl[r][c4 + 3] = f2bf(v.w);
    __syncthreads();
    ushort4 o = {tl[c4 + 0][r], tl[c4 + 1][r], tl[c4 + 2][r], tl[c4 + 3][r]};
    *(ushort4*)&Wt[(size_t)(n0 + r) * Kd + k0 + c4] = o;
}

// ---------------------------------------------------------------------------
// bf16 MFMA GEMM core: C[128x128] per block, BK=32, 4 waves (2x2 of 64x64),
// A [M][K] bf16 row-major, Bt [N][K] bf16 row-major (i.e. B transposed).
// m97 structure: global_load_lds(16B) staging, ds_read_b128 frags, fp32 acc.
// ---------------------------------------------------------------------------
#define GEMM_CORE(A_, Bt_, Kd_, row0_, col0_)                                 \
    __shared__ unsigned short As[128 * 32];                                   \
    __shared__ unsigned short Bs[128 * 32];                                   \
    const int t    = threadIdx.x;                                             \
    const int lane = t & 63;                                                  \
    const int w    = t >> 6;                                                  \
    const int l15  = lane & 15;                                               \
    const int quad = lane >> 4;                                               \
    const int wm   = w >> 1, wn = w & 1;                                      \
    size_t aOff = (size_t)(row0_ + w * 16 + (lane >> 2)) * Kd_ + (lane & 3) * 8; \
    size_t bOff = (size_t)(col0_ + w * 16 + (lane >> 2)) * Kd_ + (lane & 3) * 8; \
    floatx4 acc[4][4];                                                        \
    _Pragma("unroll")                                                         \
    for (int i = 0; i < 4; ++i)                                               \
        _Pragma("unroll")                                                     \
        for (int j = 0; j < 4; ++j) acc[i][j] = floatx4{0.f, 0.f, 0.f, 0.f};  \
    for (int k0 = 0; k0 < Kd_; k0 += 32) {                                    \
        _Pragma("unroll")                                                     \
        for (int c = 0; c < 2; ++c) {                                         \
            g2l16(&A_[aOff + (size_t)c * 64 * Kd_ + k0],                      \
                  &As[(w * 16 + c * 64) * 32]);                               \
            g2l16(&Bt_[bOff + (size_t)c * 64 * Kd_ + k0],                     \
                  &Bs[(w * 16 + c * 64) * 32]);                               \
        }                                                                     \
        __syncthreads();                                                      \
        short8 af[4], bf[4];                                                  \
        _Pragma("unroll")                                                     \
        for (int i = 0; i < 4; ++i)                                           \
            af[i] = *(const short8*)&As[(wm * 64 + i * 16 + l15) * 32 + quad * 8]; \
        _Pragma("unroll")                                                     \
        for (int j = 0; j < 4; ++j)                                           \
            bf[j] = *(const short8*)&Bs[(wn * 64 + j * 16 + l15) * 32 + quad * 8]; \
        _Pragma("unroll")                                                     \
        for (int i = 0; i < 4; ++i)                                           \
            _Pragma("unroll")                                                 \
            for (int j = 0; j < 4; ++j)                                       \
                acc[i][j] = __builtin_amdgcn_mfma_f32_16x16x32_bf16(          \
                    af[i], bf[j], acc[i][j], 0, 0, 0);                        \
        __syncthreads();                                                      \
    }

// Kernel 1: qkv = x @ W_qkv (bf16 in, fp32 acc), scatter bf16 to q/k/v [B,H,N,64]
__global__ __launch_bounds__(256) void gemm_qkv_kernel(
    const unsigned short* __restrict__ X,    // [4096][1024] bf16
    const unsigned short* __restrict__ Wt,   // [3072][1024] bf16 (W^T)
    unsigned short* __restrict__ qb, unsigned short* __restrict__ kb,
    unsigned short* __restrict__ vb)
{
    const int row0 = blockIdx.y * 128;
    const int col0 = blockIdx.x * 128;
    GEMM_CORE(X, Wt, 1024, row0, col0)
    // epilogue: C/D frag (i,j) reg r -> row = wm*64+i*16+quad*4+r, col = wn*64+j*16+l15
    #pragma unroll
    for (int j = 0; j < 4; ++j) {
        const int gcol = col0 + wn * 64 + j * 16 + l15;
        const int which = gcol >> 10;
        const int rem = gcol & 1023;
        const int h = rem >> 6, d = rem & 63;
        unsigned short* dstbuf = (which == 0) ? qb : (which == 1) ? kb : vb;
        #pragma unroll
        for (int i = 0; i < 4; ++i) {
            #pragma unroll
            for (int r = 0; r < 4; ++r) {
                const int grow = row0 + wm * 64 + i * 16 + quad * 4 + r;
                const int bidx = grow >> 11, n = grow & 2047;
                dstbuf[(((size_t)(bidx * H_ + h) * N_ + n) * HD_) + d] =
                    f2bf(acc[i][j][r]);
            }
        }
    }
}

// Kernel 4: out = o @ W_proj + b_proj (bf16 in, fp32 acc/out)
__global__ __launch_bounds__(256) void gemm_proj_kernel(
    const unsigned short* __restrict__ O,    // [4096][1024] bf16
    const unsigned short* __restrict__ Wt,   // [1024][1024] bf16 (W^T)
    const float* __restrict__ bias, float* __restrict__ out)
{
    const int row0 = blockIdx.y * 128;
    const int col0 = blockIdx.x * 128;
    GEMM_CORE(O, Wt, 1024, row0, col0)
    #pragma unroll
    for (int j = 0; j < 4; ++j) {
        const int gcol = col0 + wn * 64 + j * 16 + l15;
        const float b = bias[gcol];
        #pragma unroll
        for (int i = 0; i < 4; ++i) {
            #pragma unroll
            for (int r = 0; r < 4; ++r) {
                const int grow = row0 + wm * 64 + i * 16 + quad * 4 + r;
                out[(size_t)grow * 1024 + gcol] = acc[i][j][r] + b;
            }
        }
    }
}

// ---------------------------------------------------------------------------
// Kernel 2: LayerNorm over hd=64 for q and k (bf16 in/out, fp32 math).
// ---------------------------------------------------------------------------
__global__ __launch_bounds__(256) void ln_kernel(
    unsigned short* __restrict__ qb, unsigned short* __restrict__ kb,
    const float* __restrict__ qw, const float* __restrict__ qbi,
    const float* __restrict__ kw, const float* __restrict__ kbi)
{
    const int lane = threadIdx.x & 63;
    const int w    = threadIdx.x >> 6;
    const int row  = blockIdx.x * 4 + w;
    const bool isq = (blockIdx.y == 0);
    unsigned short* p = (isq ? qb : kb) + (size_t)row * 64 + lane;
    const float* wt = isq ? qw : kw;
    const float* bi = isq ? qbi : kbi;
    float v = bf2f(*p);
    float s = v;
    #pragma unroll
    for (int o = 1; o < 64; o <<= 1) s += __shfl_xor(s, o);
    const float mu = s * (1.0f / 64.0f);
    const float d  = v - mu;
    float s2 = d * d;
    #pragma unroll
    for (int o = 1; o < 64; o <<= 1) s2 += __shfl_xor(s2, o);
    const float var = s2 * (1.0f / 64.0f);
    float y = d * rsqrtf(var + 1e-5f) * wt[lane] + bi[lane];
    if (isq) y *= 0.125f;
    *p = f2bf(y);
}

// ---------------------------------------------------------------------------
// Kernel 3: flash attention, bf16 MFMA (16x16x32). Writes ob bf16 [B,N,C].
// ---------------------------------------------------------------------------
__global__ __launch_bounds__(256) void flash_kernel(
    const unsigned short* __restrict__ qb, const unsigned short* __restrict__ kb,
    const unsigned short* __restrict__ vb, unsigned short* __restrict__ ob)
{
    __shared__ __align__(16) unsigned short Ks[64][72];
    __shared__ __align__(16) unsigned short Vt[64][72];   // transposed: [d][kv]
    __shared__ __align__(16) unsigned short QPs[64][72];  // Q tile, then P
    const int t    = threadIdx.x;
    const int lane = t & 63;
    const int w    = t >> 6;
    const int l15  = lane & 15;
    const int quad = lane >> 4;
    const int q0   = blockIdx.x * 64;
    const int bh   = blockIdx.y;
    const unsigned short* Q = qb + (size_t)bh * N_ * HD_;
    const unsigned short* K = kb + (size_t)bh * N_ * HD_;
    const unsigned short* V = vb + (size_t)bh * N_ * HD_;

    {
        const int r = t >> 3, c0 = (t & 7) * 8;
        *(short8*)&QPs[r][c0]      = *(const short8*)&Q[(size_t)(q0 + r) * 64 + c0];
        *(short8*)&QPs[r + 32][c0] = *(const short8*)&Q[(size_t)(q0 + r + 32) * 64 + c0];
    }
    __syncthreads();
    short8 qa0 = *(const short8*)&QPs[16 * w + l15][quad * 8];
    short8 qa1 = *(const short8*)&QPs[16 * w + l15][32 + quad * 8];

    floatx4 acc[4] = {floatx4{0,0,0,0}, floatx4{0,0,0,0},
                      floatx4{0,0,0,0}, floatx4{0,0,0,0}};
    float m_i[4] = {-1e30f, -1e30f, -1e30f, -1e30f};
    float l_i[4] = {0.f, 0.f, 0.f, 0.f};

    for (int kt = 0; kt < N_; kt += 64) {
        __syncthreads();
        {
            const int r = t >> 3, c0 = (t & 7) * 8;
            *(short8*)&Ks[r][c0]      = *(const short8*)&K[(size_t)(kt + r) * 64 + c0];
            *(short8*)&Ks[r + 32][c0] = *(const short8*)&K[(size_t)(kt + r + 32) * 64 + c0];
            const int vr = (t & 31) * 2, vc = (t >> 5) * 8;
            short8 v0 = *(const short8*)&V[(size_t)(kt + vr) * 64 + vc];
            short8 v1 = *(const short8*)&V[(size_t)(kt + vr + 1) * 64 + vc];
            #pragma unroll
            for (int j = 0; j < 8; ++j) {
                unsigned int pk = (unsigned short)v0[j] |
                                  ((unsigned int)(unsigned short)v1[j] << 16);
                *(unsigned int*)&Vt[vc + j][vr] = pk;
            }
        }
        __syncthreads();

        floatx4 sc[4];
        #pragma unroll
        for (int ct = 0; ct < 4; ++ct) {
            short8 b0 = *(const short8*)&Ks[ct * 16 + l15][quad * 8];
            short8 b1 = *(const short8*)&Ks[ct * 16 + l15][32 + quad * 8];
            floatx4 r = {0.f, 0.f, 0.f, 0.f};
            r = __builtin_amdgcn_mfma_f32_16x16x32_bf16(qa0, b0, r, 0, 0, 0);
            r = __builtin_amdgcn_mfma_f32_16x16x32_bf16(qa1, b1, r, 0, 0, 0);
            sc[ct] = r;
        }

        float alpha[4];
        #pragma unroll
        for (int r = 0; r < 4; ++r) {
            float mx = fmaxf(fmaxf(sc[0][r], sc[1][r]), fmaxf(sc[2][r], sc[3][r]));
            #pragma unroll
            for (int o = 1; o < 16; o <<= 1) mx = fmaxf(mx, __shfl_xor(mx, o));
            const float m_new = fmaxf(m_i[r], mx);
            float p[4], sum = 0.f;
            #pragma unroll
            for (int ct = 0; ct < 4; ++ct) {
                p[ct] = __expf(sc[ct][r] - m_new);
                sum += p[ct];
            }
            #pragma unroll
            for (int o = 1; o < 16; o <<= 1) sum += __shfl_xor(sum, o);
            alpha[r] = __expf(m_i[r] - m_new);
            l_i[r] = l_i[r] * alpha[r] + sum;
            m_i[r] = m_new;
            const int prow = 16 * w + quad * 4 + r;
            #pragma unroll
            for (int ct = 0; ct < 4; ++ct)
                QPs[prow][ct * 16 + l15] = f2bf(p[ct]);
        }
        #pragma unroll
        for (int dt = 0; dt < 4; ++dt)
            #pragma unroll
            for (int r = 0; r < 4; ++r) acc[dt][r] *= alpha[r];

        asm volatile("" ::: "memory");

        #pragma unroll
        for (int kk = 0; kk < 2; ++kk) {
            short8 pa = *(const short8*)&QPs[16 * w + l15][kk * 32 + quad * 8];
            #pragma unroll
            for (int dt = 0; dt < 4; ++dt) {
                short8 vv = *(const short8*)&Vt[dt * 16 + l15][kk * 32 + quad * 8];
                acc[dt] = __builtin_amdgcn_mfma_f32_16x16x32_bf16(pa, vv, acc[dt], 0, 0, 0);
            }
        }
    }

    const int bidx = bh >> 4, h = bh & 15;
    #pragma unroll
    for (int r = 0; r < 4; ++r) {
        const int n = q0 + 16 * w + quad * 4 + r;
        const float inv = 1.0f / l_i[r];
        #pragma unroll
        for (int dt = 0; dt < 4; ++dt)
            ob[((size_t)(bidx * N_ + n)) * C_ + h * 64 + dt * 16 + l15] =
                f2bf(acc[dt][r] * inv);
    }
}

// ---------------------------------------------------------------------------
extern "C" void kernel_launch(void* const* d_in, const int* in_sizes, int n_in,
                              void* d_out, int out_size, void* d_ws, size_t ws_size,
                              hipStream_t stream) {
    const float* x      = (const float*)d_in[0];
    const float* W_qkv  = (const float*)d_in[1];
    const float* qn_w   = (const float*)d_in[2];
    const float* qn_b   = (const float*)d_in[3];
    const float* kn_w   = (const float*)d_in[4];
    const float* kn_b   = (const float*)d_in[5];
    const float* W_proj = (const float*)d_in[6];
    const float* b_proj = (const float*)d_in[7];
    float* out = (float*)d_out;

    unsigned short* qb  = (unsigned short*)d_ws;               // 3 x QSZ bf16
    unsigned short* kb  = qb + (size_t)QSZ;
    unsigned short* vb  = kb + (size_t)QSZ;
    unsigned short* ob  = vb + (size_t)QSZ;                    // [B,N,C] bf16
    unsigned short* xb  = ob + (size_t)B_ * N_ * C_;           // [4096][1024]
    unsigned short* wqt = xb + (size_t)B_ * N_ * C_;           // [3072][1024]
    unsigned short* wpt = wqt + (size_t)3 * C_ * C_;           // [1024][1024]

    // 0) pack / transpose weights+activations to bf16
    pack_bf16_kernel<<<dim3((B_ * N_ * C_) / 1024), 256, 0, stream>>>(x, xb);
    transpose_pack_kernel<<<dim3(96, 32), 256, 0, stream>>>(W_qkv, wqt, 1024, 3072);
    transpose_pack_kernel<<<dim3(32, 32), 256, 0, stream>>>(W_proj, wpt, 1024, 1024);
    // 1) qkv GEMM (MFMA) -> q/k/v bf16 [B,H,N,64]
    gemm_qkv_kernel<<<dim3(24, 32), 256, 0, stream>>>(xb, wqt, qb, kb, vb);
    // 2) LayerNorm q,k
    ln_kernel<<<dim3((B_ * H_ * N_) / 4, 2), 256, 0, stream>>>(qb, kb, qn_w, qn_b, kn_w, kn_b);
    // 3) flash attention -> ob bf16 [B,N,C]
    flash_kernel<<<dim3(N_ / 64, B_ * H_), 256, 0, stream>>>(qb, kb, vb, ob);
    // 4) output projection (MFMA) + bias -> fp32 out
    gemm_proj_kernel<<<dim3(8, 32), 256, 0, stream>>>(ob, wpt, b_proj, out);
}

// Round 4
// 261.660 us; speedup vs baseline: 5.0872x; 1.1030x over previous
//
#include <hip/hip_runtime.h>
#include <hip/hip_bf16.h>

#define B_  2
#define N_  2048
#define C_  1024
#define H_  16
#define HD_ 64
#define QSZ (B_*H_*N_*HD_)   // elements per q/k/v buffer

typedef __attribute__((ext_vector_type(8))) short short8;            // 8 bf16
typedef __attribute__((ext_vector_type(4))) float floatx4;
typedef __attribute__((ext_vector_type(4))) unsigned short ushort4v; // 4 bf16

__device__ __forceinline__ unsigned short f2bf(float f) {
    unsigned int u = __builtin_bit_cast(unsigned int, f);
    u += 0x7fff + ((u >> 16) & 1);          // round-to-nearest-even
    return (unsigned short)(u >> 16);
}
__device__ __forceinline__ float bf2f(unsigned short h) {
    return __builtin_bit_cast(float, (unsigned int)h << 16);
}

// async global->LDS, 16 B per lane; LDS dest = wave-uniform base + lane*16
__device__ __forceinline__ void g2l16(const void* g, void* l) {
    __builtin_amdgcn_global_load_lds(
        (const __attribute__((address_space(1))) void*)g,
        (__attribute__((address_space(3))) void*)l, 16, 0, 0);
}

// ---------------------------------------------------------------------------
// pack fp32 -> bf16, same layout
// ---------------------------------------------------------------------------
__global__ __launch_bounds__(256) void pack_bf16_kernel(
    const float* __restrict__ src, unsigned short* __restrict__ dst)
{
    const int i = blockIdx.x * 256 + threadIdx.x;
    float4 v = ((const float4*)src)[i];
    ushort4 o = {f2bf(v.x), f2bf(v.y), f2bf(v.z), f2bf(v.w)};
    ((ushort4*)dst)[i] = o;
}

// ---------------------------------------------------------------------------
// transpose + pack: W fp32 [Kd][Nd] -> Wt bf16 [Nd][Kd]
// ---------------------------------------------------------------------------
__global__ __launch_bounds__(256) void transpose_pack_kernel(
    const float* __restrict__ W, unsigned short* __restrict__ Wt,
    int Kd, int Nd)
{
    __shared__ unsigned short tl[32][34];
    const int r  = threadIdx.x >> 3;
    const int c4 = (threadIdx.x & 7) * 4;
    const int n0 = blockIdx.x * 32, k0 = blockIdx.y * 32;
    float4 v = *(const float4*)&W[(size_t)(k0 + r) * Nd + n0 + c4];
    tl[r][c4 + 0] = f2bf(v.x); tl[r][c4 + 1] = f2bf(v.y);
    tl[r][c4 + 2] = f2bf(v.z); tl[r][c4 + 3] = f2bf(v.w);
    __syncthreads();
    ushort4 o = {tl[c4 + 0][r], tl[c4 + 1][r], tl[c4 + 2][r], tl[c4 + 3][r]};
    *(ushort4*)&Wt[(size_t)(n0 + r) * Kd + k0 + c4] = o;
}

// ---------------------------------------------------------------------------
// bf16 MFMA GEMM core (m97 structure): 128x128 tile, BK=32, 4 waves
// ---------------------------------------------------------------------------
#define GEMM_CORE(A_, Bt_, Kd_, row0_, col0_)                                 \
    __shared__ unsigned short As[128 * 32];                                   \
    __shared__ unsigned short Bs[128 * 32];                                   \
    const int t    = threadIdx.x;                                             \
    const int lane = t & 63;                                                  \
    const int w    = t >> 6;                                                  \
    const int l15  = lane & 15;                                               \
    const int quad = lane >> 4;                                               \
    const int wm   = w >> 1, wn = w & 1;                                      \
    size_t aOff = (size_t)(row0_ + w * 16 + (lane >> 2)) * Kd_ + (lane & 3) * 8; \
    size_t bOff = (size_t)(col0_ + w * 16 + (lane >> 2)) * Kd_ + (lane & 3) * 8; \
    floatx4 acc[4][4];                                                        \
    _Pragma("unroll")                                                         \
    for (int i = 0; i < 4; ++i)                                               \
        _Pragma("unroll")                                                     \
        for (int j = 0; j < 4; ++j) acc[i][j] = floatx4{0.f, 0.f, 0.f, 0.f};  \
    for (int k0 = 0; k0 < Kd_; k0 += 32) {                                    \
        _Pragma("unroll")                                                     \
        for (int c = 0; c < 2; ++c) {                                         \
            g2l16(&A_[aOff + (size_t)c * 64 * Kd_ + k0],                      \
                  &As[(w * 16 + c * 64) * 32]);                               \
            g2l16(&Bt_[bOff + (size_t)c * 64 * Kd_ + k0],                     \
                  &Bs[(w * 16 + c * 64) * 32]);                               \
        }                                                                     \
        __syncthreads();                                                      \
        short8 af[4], bf[4];                                                  \
        _Pragma("unroll")                                                     \
        for (int i = 0; i < 4; ++i)                                           \
            af[i] = *(const short8*)&As[(wm * 64 + i * 16 + l15) * 32 + quad * 8]; \
        _Pragma("unroll")                                                     \
        for (int j = 0; j < 4; ++j)                                           \
            bf[j] = *(const short8*)&Bs[(wn * 64 + j * 16 + l15) * 32 + quad * 8]; \
        _Pragma("unroll")                                                     \
        for (int i = 0; i < 4; ++i)                                           \
            _Pragma("unroll")                                                 \
            for (int j = 0; j < 4; ++j)                                       \
                acc[i][j] = __builtin_amdgcn_mfma_f32_16x16x32_bf16(          \
                    af[i], bf[j], acc[i][j], 0, 0, 0);                        \
        __syncthreads();                                                      \
    }

__global__ __launch_bounds__(256) void gemm_qkv_kernel(
    const unsigned short* __restrict__ X,    // [4096][1024] bf16
    const unsigned short* __restrict__ Wt,   // [3072][1024] bf16 (W^T)
    unsigned short* __restrict__ qb, unsigned short* __restrict__ kb,
    unsigned short* __restrict__ vb)
{
    const int row0 = blockIdx.y * 128;
    const int col0 = blockIdx.x * 128;
    GEMM_CORE(X, Wt, 1024, row0, col0)
    #pragma unroll
    for (int j = 0; j < 4; ++j) {
        const int gcol = col0 + wn * 64 + j * 16 + l15;
        const int which = gcol >> 10;
        const int rem = gcol & 1023;
        const int h = rem >> 6, d = rem & 63;
        unsigned short* dstbuf = (which == 0) ? qb : (which == 1) ? kb : vb;
        #pragma unroll
        for (int i = 0; i < 4; ++i) {
            #pragma unroll
            for (int r = 0; r < 4; ++r) {
                const int grow = row0 + wm * 64 + i * 16 + quad * 4 + r;
                const int bidx = grow >> 11, n = grow & 2047;
                dstbuf[(((size_t)(bidx * H_ + h) * N_ + n) * HD_) + d] =
                    f2bf(acc[i][j][r]);
            }
        }
    }
}

__global__ __launch_bounds__(256) void gemm_proj_kernel(
    const unsigned short* __restrict__ O,    // [4096][1024] bf16
    const unsigned short* __restrict__ Wt,   // [1024][1024] bf16 (W^T)
    const float* __restrict__ bias, float* __restrict__ out)
{
    const int row0 = blockIdx.y * 128;
    const int col0 = blockIdx.x * 128;
    GEMM_CORE(O, Wt, 1024, row0, col0)
    #pragma unroll
    for (int j = 0; j < 4; ++j) {
        const int gcol = col0 + wn * 64 + j * 16 + l15;
        const float b = bias[gcol];
        #pragma unroll
        for (int i = 0; i < 4; ++i) {
            #pragma unroll
            for (int r = 0; r < 4; ++r) {
                const int grow = row0 + wm * 64 + i * 16 + quad * 4 + r;
                out[(size_t)grow * 1024 + gcol] = acc[i][j][r] + b;
            }
        }
    }
}

// ---------------------------------------------------------------------------
// Kernel 2: LayerNorm over hd=64 for q and k (bf16 in/out, fp32 math).
// ---------------------------------------------------------------------------
__global__ __launch_bounds__(256) void ln_kernel(
    unsigned short* __restrict__ qb, unsigned short* __restrict__ kb,
    const float* __restrict__ qw, const float* __restrict__ qbi,
    const float* __restrict__ kw, const float* __restrict__ kbi)
{
    const int lane = threadIdx.x & 63;
    const int w    = threadIdx.x >> 6;
    const int row  = blockIdx.x * 4 + w;
    const bool isq = (blockIdx.y == 0);
    unsigned short* p = (isq ? qb : kb) + (size_t)row * 64 + lane;
    const float* wt = isq ? qw : kw;
    const float* bi = isq ? qbi : kbi;
    float v = bf2f(*p);
    float s = v;
    #pragma unroll
    for (int o = 1; o < 64; o <<= 1) s += __shfl_xor(s, o);
    const float mu = s * (1.0f / 64.0f);
    const float d  = v - mu;
    float s2 = d * d;
    #pragma unroll
    for (int o = 1; o < 64; o <<= 1) s2 += __shfl_xor(s2, o);
    const float var = s2 * (1.0f / 64.0f);
    float y = d * rsqrtf(var + 1e-5f) * wt[lane] + bi[lane];
    if (isq) y *= 0.125f;
    *p = f2bf(y);
}

// ---------------------------------------------------------------------------
// Kernel 3: flash attention v2 — transposed-S softmax.
// Block = 256 thr = 4 waves; Q-tile 128 rows (32/wave, qt=0,1); kv-tile 64.
// S^T = K·Q^T  (C/D: col=q, row=kv)  ->  per-lane softmax over own q col.
// O^T = V^T·P (A=Vt LDS-transposed, B=P rows, wave-private LDS round trip).
// LDS rows padded to 72 bf16 (144 B).
// ---------------------------------------------------------------------------
__global__ __launch_bounds__(256) void flash_kernel(
    const unsigned short* __restrict__ qb, const unsigned short* __restrict__ kb,
    const unsigned short* __restrict__ vb, unsigned short* __restrict__ ob)
{
    __shared__ __align__(16) unsigned short Ks[64 * 72];
    __shared__ __align__(16) unsigned short Vt[64 * 72];   // [d][kv]
    __shared__ __align__(16) unsigned short Ps[128 * 72];  // Q stage -> P -> O
    const int t    = threadIdx.x;
    const int lane = t & 63;
    const int w    = t >> 6;
    const int l15  = lane & 15;
    const int quad = lane >> 4;
    const int q0   = blockIdx.x * 128;
    const int bh   = blockIdx.y;
    const unsigned short* Q = qb + (size_t)bh * N_ * HD_;
    const unsigned short* K = kb + (size_t)bh * N_ * HD_;
    const unsigned short* V = vb + (size_t)bh * N_ * HD_;

    // stage Q (128x64) into Ps
    {
        const int r = t >> 3, c = (t & 7) * 8;
        #pragma unroll
        for (int rep = 0; rep < 4; ++rep)
            *(short8*)&Ps[(rep * 32 + r) * 72 + c] =
                *(const short8*)&Q[(size_t)(q0 + rep * 32 + r) * 64 + c];
    }
    __syncthreads();
    // Q fragments (B-operand): rows w*32 + qt*16 + l15
    short8 qf[2][2];
    #pragma unroll
    for (int qt = 0; qt < 2; ++qt)
        #pragma unroll
        for (int kk = 0; kk < 2; ++kk)
            qf[qt][kk] = *(const short8*)
                &Ps[(w * 32 + qt * 16 + l15) * 72 + kk * 32 + quad * 8];

    floatx4 acc[2][4];
    #pragma unroll
    for (int qt = 0; qt < 2; ++qt)
        #pragma unroll
        for (int dt = 0; dt < 4; ++dt) acc[qt][dt] = floatx4{0.f, 0.f, 0.f, 0.f};
    float m_i[2] = {-1e30f, -1e30f};
    float l_i[2] = {0.f, 0.f};

    for (int kt = 0; kt < N_; kt += 64) {
        __syncthreads();   // prior iteration's Ks/Vt reads complete
        {
            // K rows -> Ks
            const int r = t >> 3, c = (t & 7) * 8;
            *(short8*)&Ks[r * 72 + c] =
                *(const short8*)&K[(size_t)(kt + r) * 64 + c];
            *(short8*)&Ks[(r + 32) * 72 + c] =
                *(const short8*)&K[(size_t)(kt + r + 32) * 64 + c];
            // V -> Vt (transposed), packed uint2 writes
            const int vc = (t & 15) * 4, vr = (t >> 4) * 4;
            ushort4v r0 = *(const ushort4v*)&V[(size_t)(kt + vr + 0) * 64 + vc];
            ushort4v r1 = *(const ushort4v*)&V[(size_t)(kt + vr + 1) * 64 + vc];
            ushort4v r2 = *(const ushort4v*)&V[(size_t)(kt + vr + 2) * 64 + vc];
            ushort4v r3 = *(const ushort4v*)&V[(size_t)(kt + vr + 3) * 64 + vc];
            #pragma unroll
            for (int j = 0; j < 4; ++j) {
                uint2 u;
                u.x = (unsigned int)r0[j] | ((unsigned int)r1[j] << 16);
                u.y = (unsigned int)r2[j] | ((unsigned int)r3[j] << 16);
                *(uint2*)&Vt[(vc + j) * 72 + vr] = u;
            }
        }
        __syncthreads();

        // S^T = K . Q^T : rows kv (A=K), cols q (B=Q)
        floatx4 sc[2][4];
        #pragma unroll
        for (int ct = 0; ct < 4; ++ct) {
            short8 a0 = *(const short8*)&Ks[(ct * 16 + l15) * 72 + quad * 8];
            short8 a1 = *(const short8*)&Ks[(ct * 16 + l15) * 72 + 32 + quad * 8];
            #pragma unroll
            for (int qt = 0; qt < 2; ++qt) {
                floatx4 r = {0.f, 0.f, 0.f, 0.f};
                r = __builtin_amdgcn_mfma_f32_16x16x32_bf16(a0, qf[qt][0], r, 0, 0, 0);
                r = __builtin_amdgcn_mfma_f32_16x16x32_bf16(a1, qf[qt][1], r, 0, 0, 0);
                sc[qt][ct] = r;
            }
        }

        // transposed softmax: lane owns q-col l15; 16 kv vals in regs,
        // cross-quad reduce = 2 shuffles
        #pragma unroll
        for (int qt = 0; qt < 2; ++qt) {
            float mx = -1e30f;
            #pragma unroll
            for (int ct = 0; ct < 4; ++ct)
                #pragma unroll
                for (int r = 0; r < 4; ++r) mx = fmaxf(mx, sc[qt][ct][r]);
            mx = fmaxf(mx, __shfl_xor(mx, 16));
            mx = fmaxf(mx, __shfl_xor(mx, 32));
            const float m_new = fmaxf(m_i[qt], mx);
            float sum = 0.f;
            #pragma unroll
            for (int ct = 0; ct < 4; ++ct)
                #pragma unroll
                for (int r = 0; r < 4; ++r) {
                    const float p = __expf(sc[qt][ct][r] - m_new);
                    sc[qt][ct][r] = p;
                    sum += p;
                }
            sum += __shfl_xor(sum, 16);
            sum += __shfl_xor(sum, 32);
            const float alpha = __expf(m_i[qt] - m_new);
            l_i[qt] = l_i[qt] * alpha + sum;
            m_i[qt] = m_new;
            #pragma unroll
            for (int dt = 0; dt < 4; ++dt) acc[qt][dt] *= alpha;
            // write P row (own q row), packed b64
            const int prow = w * 32 + qt * 16 + l15;
            #pragma unroll
            for (int ct = 0; ct < 4; ++ct) {
                ushort4v pk;
                pk[0] = f2bf(sc[qt][ct][0]); pk[1] = f2bf(sc[qt][ct][1]);
                pk[2] = f2bf(sc[qt][ct][2]); pk[3] = f2bf(sc[qt][ct][3]);
                *(ushort4v*)&Ps[prow * 72 + ct * 16 + quad * 4] = pk;
            }
        }
        asm volatile("" ::: "memory");

        // O^T += V^T . P : A = Vt rows (d), B = P rows (own q rows)
        #pragma unroll
        for (int kk = 0; kk < 2; ++kk) {
            short8 pb[2];
            #pragma unroll
            for (int qt = 0; qt < 2; ++qt)
                pb[qt] = *(const short8*)
                    &Ps[(w * 32 + qt * 16 + l15) * 72 + kk * 32 + quad * 8];
            #pragma unroll
            for (int dt = 0; dt < 4; ++dt) {
                short8 va = *(const short8*)
                    &Vt[(dt * 16 + l15) * 72 + kk * 32 + quad * 8];
                #pragma unroll
                for (int qt = 0; qt < 2; ++qt)
                    acc[qt][dt] = __builtin_amdgcn_mfma_f32_16x16x32_bf16(
                        va, pb[qt], acc[qt][dt], 0, 0, 0);
            }
        }
    }

    // epilogue: O^T regs -> Ps[q][d] (own rows), then coalesced copy-out
    asm volatile("" ::: "memory");
    #pragma unroll
    for (int qt = 0; qt < 2; ++qt) {
        const float inv = 1.0f / l_i[qt];
        const int orow = w * 32 + qt * 16 + l15;
        #pragma unroll
        for (int dt = 0; dt < 4; ++dt) {
            ushort4v o4;
            o4[0] = f2bf(acc[qt][dt][0] * inv);
            o4[1] = f2bf(acc[qt][dt][1] * inv);
            o4[2] = f2bf(acc[qt][dt][2] * inv);
            o4[3] = f2bf(acc[qt][dt][3] * inv);
            *(ushort4v*)&Ps[orow * 72 + dt * 16 + quad * 4] = o4;
        }
    }
    __syncthreads();
    const int bidx = bh >> 4, h = bh & 15;
    {
        const int r = t >> 3, c = (t & 7) * 8;
        #pragma unroll
        for (int rep = 0; rep < 4; ++rep) {
            const int row = rep * 32 + r;
            *(short8*)&ob[((size_t)(bidx * N_ + q0 + row)) * C_ + h * 64 + c] =
                *(const short8*)&Ps[row * 72 + c];
        }
    }
}

// ---------------------------------------------------------------------------
extern "C" void kernel_launch(void* const* d_in, const int* in_sizes, int n_in,
                              void* d_out, int out_size, void* d_ws, size_t ws_size,
                              hipStream_t stream) {
    const float* x      = (const float*)d_in[0];
    const float* W_qkv  = (const float*)d_in[1];
    const float* qn_w   = (const float*)d_in[2];
    const float* qn_b   = (const float*)d_in[3];
    const float* kn_w   = (const float*)d_in[4];
    const float* kn_b   = (const float*)d_in[5];
    const float* W_proj = (const float*)d_in[6];
    const float* b_proj = (const float*)d_in[7];
    float* out = (float*)d_out;

    unsigned short* qb  = (unsigned short*)d_ws;               // 3 x QSZ bf16
    unsigned short* kb  = qb + (size_t)QSZ;
    unsigned short* vb  = kb + (size_t)QSZ;
    unsigned short* ob  = vb + (size_t)QSZ;                    // [B,N,C] bf16
    unsigned short* xb  = ob + (size_t)B_ * N_ * C_;           // [4096][1024]
    unsigned short* wqt = xb + (size_t)B_ * N_ * C_;           // [3072][1024]
    unsigned short* wpt = wqt + (size_t)3 * C_ * C_;           // [1024][1024]

    pack_bf16_kernel<<<dim3((B_ * N_ * C_) / 1024), 256, 0, stream>>>(x, xb);
    transpose_pack_kernel<<<dim3(96, 32), 256, 0, stream>>>(W_qkv, wqt, 1024, 3072);
    transpose_pack_kernel<<<dim3(32, 32), 256, 0, stream>>>(W_proj, wpt, 1024, 1024);
    gemm_qkv_kernel<<<dim3(24, 32), 256, 0, stream>>>(xb, wqt, qb, kb, vb);
    ln_kernel<<<dim3((B_ * H_ * N_) / 4, 2), 256, 0, stream>>>(qb, kb, qn_w, qn_b, kn_w, kn_b);
    flash_kernel<<<dim3(N_ / 128, B_ * H_), 256, 0, stream>>>(qb, kb, vb, ob);
    gemm_proj_kernel<<<dim3(8, 32), 256, 0, stream>>>(ob, wpt, b_proj, out);
}

// Round 5
// 244.200 us; speedup vs baseline: 5.4509x; 1.0715x over previous
//
#include <hip/hip_runtime.h>
#include <hip/hip_bf16.h>

#define B_  2
#define N_  2048
#define C_  1024
#define H_  16
#define HD_ 64
#define QSZ (B_*H_*N_*HD_)   // elements per q/k/v buffer

typedef __attribute__((ext_vector_type(8))) short short8;            // 8 bf16
typedef __attribute__((ext_vector_type(4))) float floatx4;
typedef __attribute__((ext_vector_type(4))) unsigned short ushort4v; // 4 bf16

__device__ __forceinline__ unsigned short f2bf(float f) {
    unsigned int u = __builtin_bit_cast(unsigned int, f);
    u += 0x7fff + ((u >> 16) & 1);          // round-to-nearest-even
    return (unsigned short)(u >> 16);
}
__device__ __forceinline__ float bf2f(unsigned short h) {
    return __builtin_bit_cast(float, (unsigned int)h << 16);
}
// pack two fp32 -> two RNE bf16 in one u32 (lo = a, hi = b) via v_perm_b32
__device__ __forceinline__ unsigned int pk2bf(float a, float b) {
    unsigned int ua = __builtin_bit_cast(unsigned int, a);
    unsigned int ub = __builtin_bit_cast(unsigned int, b);
    ua += 0x7fff + ((ua >> 16) & 1);
    ub += 0x7fff + ((ub >> 16) & 1);
    return __builtin_amdgcn_perm(ub, ua, 0x07060302);
}

// async global->LDS, 16 B per lane; LDS dest = wave-uniform base + lane*16
__device__ __forceinline__ void g2l16(const void* g, void* l) {
    __builtin_amdgcn_global_load_lds(
        (const __attribute__((address_space(1))) void*)g,
        (__attribute__((address_space(3))) void*)l, 16, 0, 0);
}

// ---------------------------------------------------------------------------
// pack fp32 -> bf16, same layout
// ---------------------------------------------------------------------------
__global__ __launch_bounds__(256) void pack_bf16_kernel(
    const float* __restrict__ src, unsigned short* __restrict__ dst)
{
    const int i = blockIdx.x * 256 + threadIdx.x;
    float4 v = ((const float4*)src)[i];
    ushort4 o = {f2bf(v.x), f2bf(v.y), f2bf(v.z), f2bf(v.w)};
    ((ushort4*)dst)[i] = o;
}

// ---------------------------------------------------------------------------
// transpose + pack: W fp32 [Kd][Nd] -> Wt bf16 [Nd][Kd]
// ---------------------------------------------------------------------------
__global__ __launch_bounds__(256) void transpose_pack_kernel(
    const float* __restrict__ W, unsigned short* __restrict__ Wt,
    int Kd, int Nd)
{
    __shared__ unsigned short tl[32][34];
    const int r  = threadIdx.x >> 3;
    const int c4 = (threadIdx.x & 7) * 4;
    const int n0 = blockIdx.x * 32, k0 = blockIdx.y * 32;
    float4 v = *(const float4*)&W[(size_t)(k0 + r) * Nd + n0 + c4];
    tl[r][c4 + 0] = f2bf(v.x); tl[r][c4 + 1] = f2bf(v.y);
    tl[r][c4 + 2] = f2bf(v.z); tl[r][c4 + 3] = f2bf(v.w);
    __syncthreads();
    ushort4 o = {tl[c4 + 0][r], tl[c4 + 1][r], tl[c4 + 2][r], tl[c4 + 3][r]};
    *(ushort4*)&Wt[(size_t)(n0 + r) * Kd + k0 + c4] = o;
}

// ---------------------------------------------------------------------------
// bf16 MFMA GEMM core (m97 structure): 128x128 tile, BK=32, 4 waves
// ---------------------------------------------------------------------------
#define GEMM_CORE(A_, Bt_, Kd_, row0_, col0_)                                 \
    __shared__ unsigned short As[128 * 32];                                   \
    __shared__ unsigned short Bs[128 * 32];                                   \
    const int t    = threadIdx.x;                                             \
    const int lane = t & 63;                                                  \
    const int w    = t >> 6;                                                  \
    const int l15  = lane & 15;                                               \
    const int quad = lane >> 4;                                               \
    const int wm   = w >> 1, wn = w & 1;                                      \
    size_t aOff = (size_t)(row0_ + w * 16 + (lane >> 2)) * Kd_ + (lane & 3) * 8; \
    size_t bOff = (size_t)(col0_ + w * 16 + (lane >> 2)) * Kd_ + (lane & 3) * 8; \
    floatx4 acc[4][4];                                                        \
    _Pragma("unroll")                                                         \
    for (int i = 0; i < 4; ++i)                                               \
        _Pragma("unroll")                                                     \
        for (int j = 0; j < 4; ++j) acc[i][j] = floatx4{0.f, 0.f, 0.f, 0.f};  \
    for (int k0 = 0; k0 < Kd_; k0 += 32) {                                    \
        _Pragma("unroll")                                                     \
        for (int c = 0; c < 2; ++c) {                                         \
            g2l16(&A_[aOff + (size_t)c * 64 * Kd_ + k0],                      \
                  &As[(w * 16 + c * 64) * 32]);                               \
            g2l16(&Bt_[bOff + (size_t)c * 64 * Kd_ + k0],                     \
                  &Bs[(w * 16 + c * 64) * 32]);                               \
        }                                                                     \
        __syncthreads();                                                      \
        short8 af[4], bf[4];                                                  \
        _Pragma("unroll")                                                     \
        for (int i = 0; i < 4; ++i)                                           \
            af[i] = *(const short8*)&As[(wm * 64 + i * 16 + l15) * 32 + quad * 8]; \
        _Pragma("unroll")                                                     \
        for (int j = 0; j < 4; ++j)                                           \
            bf[j] = *(const short8*)&Bs[(wn * 64 + j * 16 + l15) * 32 + quad * 8]; \
        _Pragma("unroll")                                                     \
        for (int i = 0; i < 4; ++i)                                           \
            _Pragma("unroll")                                                 \
            for (int j = 0; j < 4; ++j)                                       \
                acc[i][j] = __builtin_amdgcn_mfma_f32_16x16x32_bf16(          \
                    af[i], bf[j], acc[i][j], 0, 0, 0);                        \
        __syncthreads();                                                      \
    }

__global__ __launch_bounds__(256) void gemm_qkv_kernel(
    const unsigned short* __restrict__ X,    // [4096][1024] bf16
    const unsigned short* __restrict__ Wt,   // [3072][1024] bf16 (W^T)
    unsigned short* __restrict__ qb, unsigned short* __restrict__ kb,
    unsigned short* __restrict__ vb)
{
    const int row0 = blockIdx.y * 128;
    const int col0 = blockIdx.x * 128;
    GEMM_CORE(X, Wt, 1024, row0, col0)
    #pragma unroll
    for (int j = 0; j < 4; ++j) {
        const int gcol = col0 + wn * 64 + j * 16 + l15;
        const int which = gcol >> 10;
        const int rem = gcol & 1023;
        const int h = rem >> 6, d = rem & 63;
        unsigned short* dstbuf = (which == 0) ? qb : (which == 1) ? kb : vb;
        #pragma unroll
        for (int i = 0; i < 4; ++i) {
            #pragma unroll
            for (int r = 0; r < 4; ++r) {
                const int grow = row0 + wm * 64 + i * 16 + quad * 4 + r;
                const int bidx = grow >> 11, n = grow & 2047;
                dstbuf[(((size_t)(bidx * H_ + h) * N_ + n) * HD_) + d] =
                    f2bf(acc[i][j][r]);
            }
        }
    }
}

__global__ __launch_bounds__(256) void gemm_proj_kernel(
    const unsigned short* __restrict__ O,    // [4096][1024] bf16
    const unsigned short* __restrict__ Wt,   // [1024][1024] bf16 (W^T)
    const float* __restrict__ bias, float* __restrict__ out)
{
    const int row0 = blockIdx.y * 128;
    const int col0 = blockIdx.x * 128;
    GEMM_CORE(O, Wt, 1024, row0, col0)
    #pragma unroll
    for (int j = 0; j < 4; ++j) {
        const int gcol = col0 + wn * 64 + j * 16 + l15;
        const float b = bias[gcol];
        #pragma unroll
        for (int i = 0; i < 4; ++i) {
            #pragma unroll
            for (int r = 0; r < 4; ++r) {
                const int grow = row0 + wm * 64 + i * 16 + quad * 4 + r;
                out[(size_t)grow * 1024 + gcol] = acc[i][j][r] + b;
            }
        }
    }
}

// ---------------------------------------------------------------------------
// Kernel 2: LayerNorm over hd=64 for q and k (bf16 in/out, fp32 math).
// q scaled by hd^-0.5 * log2(e)  (softmax runs in exp2 domain).
// ---------------------------------------------------------------------------
#define QSCALE 0.18033688011112042f   // 0.125 * log2(e)
__global__ __launch_bounds__(256) void ln_kernel(
    unsigned short* __restrict__ qb, unsigned short* __restrict__ kb,
    const float* __restrict__ qw, const float* __restrict__ qbi,
    const float* __restrict__ kw, const float* __restrict__ kbi)
{
    const int lane = threadIdx.x & 63;
    const int w    = threadIdx.x >> 6;
    const int row  = blockIdx.x * 4 + w;
    const bool isq = (blockIdx.y == 0);
    unsigned short* p = (isq ? qb : kb) + (size_t)row * 64 + lane;
    const float* wt = isq ? qw : kw;
    const float* bi = isq ? qbi : kbi;
    float v = bf2f(*p);
    float s = v;
    #pragma unroll
    for (int o = 1; o < 64; o <<= 1) s += __shfl_xor(s, o);
    const float mu = s * (1.0f / 64.0f);
    const float d  = v - mu;
    float s2 = d * d;
    #pragma unroll
    for (int o = 1; o < 64; o <<= 1) s2 += __shfl_xor(s2, o);
    const float var = s2 * (1.0f / 64.0f);
    float y = d * rsqrtf(var + 1e-5f) * wt[lane] + bi[lane];
    if (isq) y *= QSCALE;
    *p = f2bf(y);
}

// ---------------------------------------------------------------------------
// Kernel 3: flash attention v3 — 8 waves/block, transposed-S softmax.
// Block = 512 thr = 8 waves; Q-tile 128 rows (16/wave); kv-tile 64.
// S^T = K·Q^T (exp2-domain softmax, per-lane over own q col).
// O^T = V^T·P; V transpose staged conflict-free (bank = 36d+kv tiles).
// ---------------------------------------------------------------------------
__global__ __launch_bounds__(512, 4) void flash_kernel(
    const unsigned short* __restrict__ qb, const unsigned short* __restrict__ kb,
    const unsigned short* __restrict__ vb, unsigned short* __restrict__ ob)
{
    __shared__ __align__(16) unsigned short Ks[64 * 72];
    __shared__ __align__(16) unsigned short Vt[64 * 72];   // [d][kv]
    __shared__ __align__(16) unsigned short Ps[128 * 72];  // Q stage -> P -> O
    const int t    = threadIdx.x;
    const int lane = t & 63;
    const int w    = t >> 6;                 // wave 0..7, owns q rows 16w..16w+15
    const int l15  = lane & 15;
    const int quad = lane >> 4;
    const int q0   = blockIdx.x * 128;
    const int bh   = blockIdx.y;
    const unsigned short* Q = qb + (size_t)bh * N_ * HD_;
    const unsigned short* K = kb + (size_t)bh * N_ * HD_;
    const unsigned short* V = vb + (size_t)bh * N_ * HD_;

    // stage Q (128x64) into Ps: 512 thr x 2 reps x short8
    {
        const int r = t >> 3, c = (t & 7) * 8;
        *(short8*)&Ps[r * 72 + c] =
            *(const short8*)&Q[(size_t)(q0 + r) * 64 + c];
        *(short8*)&Ps[(r + 64) * 72 + c] =
            *(const short8*)&Q[(size_t)(q0 + r + 64) * 64 + c];
    }
    __syncthreads();
    // Q fragment (B-operand): own row 16w + l15
    short8 qf[2];
    #pragma unroll
    for (int kk = 0; kk < 2; ++kk)
        qf[kk] = *(const short8*)&Ps[(w * 16 + l15) * 72 + kk * 32 + quad * 8];

    floatx4 acc[4];
    #pragma unroll
    for (int dt = 0; dt < 4; ++dt) acc[dt] = floatx4{0.f, 0.f, 0.f, 0.f};
    float m_i = -1e30f, l_i = 0.f;

    // V-transpose staging coords: thread owns kv pair x 4 d
    const int kvb = (t & 31) * 2;        // kv base (0..62)
    const int db  = (t >> 5) * 4;        // d base  (0..60)

    for (int kt = 0; kt < N_; kt += 64) {
        __syncthreads();   // prior iteration's Ks/Vt reads complete
        {
            // K rows -> Ks (conflict-free per octet)
            const int r = t >> 3, c = (t & 7) * 8;
            *(short8*)&Ks[r * 72 + c] =
                *(const short8*)&K[(size_t)(kt + r) * 64 + c];
            // V -> Vt transposed: uint writes, bank=(36(db+j)+kvb/..) tiles 32
            ushort4v r0 = *(const ushort4v*)&V[(size_t)(kt + kvb + 0) * 64 + db];
            ushort4v r1 = *(const ushort4v*)&V[(size_t)(kt + kvb + 1) * 64 + db];
            #pragma unroll
            for (int j = 0; j < 4; ++j) {
                unsigned int pk = (unsigned int)r0[j] | ((unsigned int)r1[j] << 16);
                *(unsigned int*)&Vt[(db + j) * 72 + kvb] = pk;
            }
        }
        __syncthreads();

        // S^T = K . Q^T : rows kv (A=K rows), col q (B=own Q row)
        floatx4 sc[4];
        #pragma unroll
        for (int ct = 0; ct < 4; ++ct) {
            short8 a0 = *(const short8*)&Ks[(ct * 16 + l15) * 72 + quad * 8];
            short8 a1 = *(const short8*)&Ks[(ct * 16 + l15) * 72 + 32 + quad * 8];
            floatx4 r = {0.f, 0.f, 0.f, 0.f};
            r = __builtin_amdgcn_mfma_f32_16x16x32_bf16(a0, qf[0], r, 0, 0, 0);
            r = __builtin_amdgcn_mfma_f32_16x16x32_bf16(a1, qf[1], r, 0, 0, 0);
            sc[ct] = r;
        }

        // exp2-domain online softmax: lane owns q col (16 kv vals in regs)
        {
            float mx = m_i;
            #pragma unroll
            for (int ct = 0; ct < 4; ++ct)
                #pragma unroll
                for (int r = 0; r < 4; ++r) mx = fmaxf(mx, sc[ct][r]);
            mx = fmaxf(mx, __shfl_xor(mx, 16));
            mx = fmaxf(mx, __shfl_xor(mx, 32));
            float sum = 0.f;
            #pragma unroll
            for (int ct = 0; ct < 4; ++ct)
                #pragma unroll
                for (int r = 0; r < 4; ++r) {
                    const float p = __builtin_amdgcn_exp2f(sc[ct][r] - mx);
                    sc[ct][r] = p;
                    sum += p;
                }
            sum += __shfl_xor(sum, 16);
            sum += __shfl_xor(sum, 32);
            const float alpha = __builtin_amdgcn_exp2f(m_i - mx);
            l_i = l_i * alpha + sum;
            m_i = mx;
            #pragma unroll
            for (int dt = 0; dt < 4; ++dt) acc[dt] *= alpha;
            // write P row (own q row), packed b64 (2-way = free)
            const int prow = w * 16 + l15;
            #pragma unroll
            for (int ct = 0; ct < 4; ++ct) {
                uint2 pk;
                pk.x = pk2bf(sc[ct][0], sc[ct][1]);
                pk.y = pk2bf(sc[ct][2], sc[ct][3]);
                *(uint2*)&Ps[prow * 72 + ct * 16 + quad * 4] = pk;
            }
        }
        asm volatile("" ::: "memory");

        // O^T += V^T . P : A = Vt rows (d), B = own P row
        #pragma unroll
        for (int kk = 0; kk < 2; ++kk) {
            short8 pb = *(const short8*)
                &Ps[(w * 16 + l15) * 72 + kk * 32 + quad * 8];
            #pragma unroll
            for (int dt = 0; dt < 4; ++dt) {
                short8 va = *(const short8*)
                    &Vt[(dt * 16 + l15) * 72 + kk * 32 + quad * 8];
                acc[dt] = __builtin_amdgcn_mfma_f32_16x16x32_bf16(
                    va, pb, acc[dt], 0, 0, 0);
            }
        }
    }

    // epilogue: O^T regs -> Ps[q][d] (own row), then coalesced copy-out
    asm volatile("" ::: "memory");
    {
        const float inv = 1.0f / l_i;
        const int orow = w * 16 + l15;
        #pragma unroll
        for (int dt = 0; dt < 4; ++dt) {
            uint2 o2;
            o2.x = pk2bf(acc[dt][0] * inv, acc[dt][1] * inv);
            o2.y = pk2bf(acc[dt][2] * inv, acc[dt][3] * inv);
            *(uint2*)&Ps[orow * 72 + dt * 16 + quad * 4] = o2;
        }
    }
    __syncthreads();
    const int bidx = bh >> 4, h = bh & 15;
    {
        const int r = t >> 3, c = (t & 7) * 8;
        *(short8*)&ob[((size_t)(bidx * N_ + q0 + r)) * C_ + h * 64 + c] =
            *(const short8*)&Ps[r * 72 + c];
        *(short8*)&ob[((size_t)(bidx * N_ + q0 + r + 64)) * C_ + h * 64 + c] =
            *(const short8*)&Ps[(r + 64) * 72 + c];
    }
}

// ---------------------------------------------------------------------------
extern "C" void kernel_launch(void* const* d_in, const int* in_sizes, int n_in,
                              void* d_out, int out_size, void* d_ws, size_t ws_size,
                              hipStream_t stream) {
    const float* x      = (const float*)d_in[0];
    const float* W_qkv  = (const float*)d_in[1];
    const float* qn_w   = (const float*)d_in[2];
    const float* qn_b   = (const float*)d_in[3];
    const float* kn_w   = (const float*)d_in[4];
    const float* kn_b   = (const float*)d_in[5];
    const float* W_proj = (const float*)d_in[6];
    const float* b_proj = (const float*)d_in[7];
    float* out = (float*)d_out;

    unsigned short* qb  = (unsigned short*)d_ws;               // 3 x QSZ bf16
    unsigned short* kb  = qb + (size_t)QSZ;
    unsigned short* vb  = kb + (size_t)QSZ;
    unsigned short* ob  = vb + (size_t)QSZ;                    // [B,N,C] bf16
    unsigned short* xb  = ob + (size_t)B_ * N_ * C_;           // [4096][1024]
    unsigned short* wqt = xb + (size_t)B_ * N_ * C_;           // [3072][1024]
    unsigned short* wpt = wqt + (size_t)3 * C_ * C_;           // [1024][1024]

    pack_bf16_kernel<<<dim3((B_ * N_ * C_) / 1024), 256, 0, stream>>>(x, xb);
    transpose_pack_kernel<<<dim3(96, 32), 256, 0, stream>>>(W_qkv, wqt, 1024, 3072);
    transpose_pack_kernel<<<dim3(32, 32), 256, 0, stream>>>(W_proj, wpt, 1024, 1024);
    gemm_qkv_kernel<<<dim3(24, 32), 256, 0, stream>>>(xb, wqt, qb, kb, vb);
    ln_kernel<<<dim3((B_ * H_ * N_) / 4, 2), 256, 0, stream>>>(qb, kb, qn_w, qn_b, kn_w, kn_b);
    flash_kernel<<<dim3(N_ / 128, B_ * H_), 512, 0, stream>>>(qb, kb, vb, ob);
    gemm_proj_kernel<<<dim3(8, 32), 256, 0, stream>>>(ob, wpt, b_proj, out);
}

// Round 6
// 226.385 us; speedup vs baseline: 5.8799x; 1.0787x over previous
//
#include <hip/hip_runtime.h>
#include <hip/hip_bf16.h>

#define B_  2
#define N_  2048
#define C_  1024
#define H_  16
#define HD_ 64
#define QSZ (B_*H_*N_*HD_)   // elements per q/k/v buffer

typedef __attribute__((ext_vector_type(8))) short short8;            // 8 bf16
typedef __attribute__((ext_vector_type(4))) float floatx4;
typedef __attribute__((ext_vector_type(4))) unsigned short ushort4v; // 4 bf16

__device__ __forceinline__ unsigned short f2bf(float f) {
    unsigned int u = __builtin_bit_cast(unsigned int, f);
    u += 0x7fff + ((u >> 16) & 1);          // round-to-nearest-even
    return (unsigned short)(u >> 16);
}
__device__ __forceinline__ float bf2f(unsigned short h) {
    return __builtin_bit_cast(float, (unsigned int)h << 16);
}
// pack two fp32 -> two RNE bf16 in one u32 (lo = a, hi = b) via v_perm_b32
__device__ __forceinline__ unsigned int pk2bf(float a, float b) {
    unsigned int ua = __builtin_bit_cast(unsigned int, a);
    unsigned int ub = __builtin_bit_cast(unsigned int, b);
    ua += 0x7fff + ((ua >> 16) & 1);
    ub += 0x7fff + ((ub >> 16) & 1);
    return __builtin_amdgcn_perm(ub, ua, 0x07060302);
}

// async global->LDS, 16 B per lane; LDS dest = wave-uniform base + lane*16
__device__ __forceinline__ void g2l16(const void* g, void* l) {
    __builtin_amdgcn_global_load_lds(
        (const __attribute__((address_space(1))) void*)g,
        (__attribute__((address_space(3))) void*)l, 16, 0, 0);
}

// ---------------------------------------------------------------------------
// pack fp32 -> bf16, same layout
// ---------------------------------------------------------------------------
__global__ __launch_bounds__(256) void pack_bf16_kernel(
    const float* __restrict__ src, unsigned short* __restrict__ dst)
{
    const int i = blockIdx.x * 256 + threadIdx.x;
    float4 v = ((const float4*)src)[i];
    ushort4 o = {f2bf(v.x), f2bf(v.y), f2bf(v.z), f2bf(v.w)};
    ((ushort4*)dst)[i] = o;
}

// ---------------------------------------------------------------------------
// transpose + pack: W fp32 [Kd][Nd] -> Wt bf16 [Nd][Kd]
// ---------------------------------------------------------------------------
__global__ __launch_bounds__(256) void transpose_pack_kernel(
    const float* __restrict__ W, unsigned short* __restrict__ Wt,
    int Kd, int Nd)
{
    __shared__ unsigned short tl[32][34];
    const int r  = threadIdx.x >> 3;
    const int c4 = (threadIdx.x & 7) * 4;
    const int n0 = blockIdx.x * 32, k0 = blockIdx.y * 32;
    float4 v = *(const float4*)&W[(size_t)(k0 + r) * Nd + n0 + c4];
    tl[r][c4 + 0] = f2bf(v.x); tl[r][c4 + 1] = f2bf(v.y);
    tl[r][c4 + 2] = f2bf(v.z); tl[r][c4 + 3] = f2bf(v.w);
    __syncthreads();
    ushort4 o = {tl[c4 + 0][r], tl[c4 + 1][r], tl[c4 + 2][r], tl[c4 + 3][r]};
    *(ushort4*)&Wt[(size_t)(n0 + r) * Kd + k0 + c4] = o;
}

// ---------------------------------------------------------------------------
// bf16 MFMA GEMM core (m97 structure): 128x128 tile, BK=32, 4 waves
// ---------------------------------------------------------------------------
#define GEMM_CORE(A_, Bt_, Kd_, row0_, col0_)                                 \
    __shared__ unsigned short As[128 * 32];                                   \
    __shared__ unsigned short Bs[128 * 32];                                   \
    const int t    = threadIdx.x;                                             \
    const int lane = t & 63;                                                  \
    const int w    = t >> 6;                                                  \
    const int l15  = lane & 15;                                               \
    const int quad = lane >> 4;                                               \
    const int wm   = w >> 1, wn = w & 1;                                      \
    size_t aOff = (size_t)(row0_ + w * 16 + (lane >> 2)) * Kd_ + (lane & 3) * 8; \
    size_t bOff = (size_t)(col0_ + w * 16 + (lane >> 2)) * Kd_ + (lane & 3) * 8; \
    floatx4 acc[4][4];                                                        \
    _Pragma("unroll")                                                         \
    for (int i = 0; i < 4; ++i)                                               \
        _Pragma("unroll")                                                     \
        for (int j = 0; j < 4; ++j) acc[i][j] = floatx4{0.f, 0.f, 0.f, 0.f};  \
    for (int k0 = 0; k0 < Kd_; k0 += 32) {                                    \
        _Pragma("unroll")                                                     \
        for (int c = 0; c < 2; ++c) {                                         \
            g2l16(&A_[aOff + (size_t)c * 64 * Kd_ + k0],                      \
                  &As[(w * 16 + c * 64) * 32]);                               \
            g2l16(&Bt_[bOff + (size_t)c * 64 * Kd_ + k0],                     \
                  &Bs[(w * 16 + c * 64) * 32]);                               \
        }                                                                     \
        __syncthreads();                                                      \
        short8 af[4], bf[4];                                                  \
        _Pragma("unroll")                                                     \
        for (int i = 0; i < 4; ++i)                                           \
            af[i] = *(const short8*)&As[(wm * 64 + i * 16 + l15) * 32 + quad * 8]; \
        _Pragma("unroll")                                                     \
        for (int j = 0; j < 4; ++j)                                           \
            bf[j] = *(const short8*)&Bs[(wn * 64 + j * 16 + l15) * 32 + quad * 8]; \
        _Pragma("unroll")                                                     \
        for (int i = 0; i < 4; ++i)                                           \
            _Pragma("unroll")                                                 \
            for (int j = 0; j < 4; ++j)                                       \
                acc[i][j] = __builtin_amdgcn_mfma_f32_16x16x32_bf16(          \
                    af[i], bf[j], acc[i][j], 0, 0, 0);                        \
        __syncthreads();                                                      \
    }

__global__ __launch_bounds__(256) void gemm_qkv_kernel(
    const unsigned short* __restrict__ X,    // [4096][1024] bf16
    const unsigned short* __restrict__ Wt,   // [3072][1024] bf16 (W^T)
    unsigned short* __restrict__ qb, unsigned short* __restrict__ kb,
    unsigned short* __restrict__ vb)
{
    const int row0 = blockIdx.y * 128;
    const int col0 = blockIdx.x * 128;
    GEMM_CORE(X, Wt, 1024, row0, col0)
    #pragma unroll
    for (int j = 0; j < 4; ++j) {
        const int gcol = col0 + wn * 64 + j * 16 + l15;
        const int which = gcol >> 10;
        const int rem = gcol & 1023;
        const int h = rem >> 6, d = rem & 63;
        unsigned short* dstbuf = (which == 0) ? qb : (which == 1) ? kb : vb;
        #pragma unroll
        for (int i = 0; i < 4; ++i) {
            #pragma unroll
            for (int r = 0; r < 4; ++r) {
                const int grow = row0 + wm * 64 + i * 16 + quad * 4 + r;
                const int bidx = grow >> 11, n = grow & 2047;
                dstbuf[(((size_t)(bidx * H_ + h) * N_ + n) * HD_) + d] =
                    f2bf(acc[i][j][r]);
            }
        }
    }
}

__global__ __launch_bounds__(256) void gemm_proj_kernel(
    const unsigned short* __restrict__ O,    // [4096][1024] bf16
    const unsigned short* __restrict__ Wt,   // [1024][1024] bf16 (W^T)
    const float* __restrict__ bias, float* __restrict__ out)
{
    const int row0 = blockIdx.y * 128;
    const int col0 = blockIdx.x * 128;
    GEMM_CORE(O, Wt, 1024, row0, col0)
    #pragma unroll
    for (int j = 0; j < 4; ++j) {
        const int gcol = col0 + wn * 64 + j * 16 + l15;
        const float b = bias[gcol];
        #pragma unroll
        for (int i = 0; i < 4; ++i) {
            #pragma unroll
            for (int r = 0; r < 4; ++r) {
                const int grow = row0 + wm * 64 + i * 16 + quad * 4 + r;
                out[(size_t)grow * 1024 + gcol] = acc[i][j][r] + b;
            }
        }
    }
}

// ---------------------------------------------------------------------------
// Kernel 2: LayerNorm over hd=64 for q and k (bf16 in/out, fp32 math).
// q scaled by hd^-0.5 * log2(e)  (softmax runs in exp2 domain).
// ---------------------------------------------------------------------------
#define QSCALE 0.18033688011112042f   // 0.125 * log2(e)
__global__ __launch_bounds__(256) void ln_kernel(
    unsigned short* __restrict__ qb, unsigned short* __restrict__ kb,
    const float* __restrict__ qw, const float* __restrict__ qbi,
    const float* __restrict__ kw, const float* __restrict__ kbi)
{
    const int lane = threadIdx.x & 63;
    const int w    = threadIdx.x >> 6;
    const int row  = blockIdx.x * 4 + w;
    const bool isq = (blockIdx.y == 0);
    unsigned short* p = (isq ? qb : kb) + (size_t)row * 64 + lane;
    const float* wt = isq ? qw : kw;
    const float* bi = isq ? qbi : kbi;
    float v = bf2f(*p);
    float s = v;
    #pragma unroll
    for (int o = 1; o < 64; o <<= 1) s += __shfl_xor(s, o);
    const float mu = s * (1.0f / 64.0f);
    const float d  = v - mu;
    float s2 = d * d;
    #pragma unroll
    for (int o = 1; o < 64; o <<= 1) s2 += __shfl_xor(s2, o);
    const float var = s2 * (1.0f / 64.0f);
    float y = d * rsqrtf(var + 1e-5f) * wt[lane] + bi[lane];
    if (isq) y *= QSCALE;
    *p = f2bf(y);
}

// ---------------------------------------------------------------------------
// Kernel 3: flash attention v4 — software-pipelined, 128-kv tiles.
// Block = 512 thr = 8 waves; Q-tile 128 (16 rows/wave); kv-tile 128.
// Per iter: barrier -> regs->LDS -> barrier -> prefetch next K/V tile into
// regs (global latency overlaps compute) -> S^T MFMA -> exp2 softmax -> PV.
// Strides: Ks 72 (144 B), Vt/Pb 136 (272 B) — 16 B aligned, minimal phases.
// LDS = 69 KB -> 2 blocks/CU.
// ---------------------------------------------------------------------------
__global__ __launch_bounds__(512, 4) void flash_kernel(
    const unsigned short* __restrict__ qb, const unsigned short* __restrict__ kb,
    const unsigned short* __restrict__ vb, unsigned short* __restrict__ ob)
{
    __shared__ __align__(16) unsigned short Ks[128 * 72];
    __shared__ __align__(16) unsigned short Vt[64 * 136];    // [d][kv]
    __shared__ __align__(16) unsigned short Pb[128 * 136];   // Q stage -> P -> O
    const int t    = threadIdx.x;
    const int lane = t & 63;
    const int w    = t >> 6;                 // wave 0..7, owns q rows 16w..16w+15
    const int l15  = lane & 15;
    const int quad = lane >> 4;
    const int q0   = blockIdx.x * 128;
    const int bh   = blockIdx.y;
    const unsigned short* Q = qb + (size_t)bh * N_ * HD_;
    const unsigned short* K = kb + (size_t)bh * N_ * HD_;
    const unsigned short* V = vb + (size_t)bh * N_ * HD_;

    // stage Q (128x64) into Pb
    {
        const int r = t >> 3, c = (t & 7) * 8;
        *(short8*)&Pb[r * 136 + c] =
            *(const short8*)&Q[(size_t)(q0 + r) * 64 + c];
        *(short8*)&Pb[(r + 64) * 136 + c] =
            *(const short8*)&Q[(size_t)(q0 + r + 64) * 64 + c];
    }
    __syncthreads();
    // Q fragment (B-operand): own row 16w + l15
    short8 qf[2];
    #pragma unroll
    for (int kk = 0; kk < 2; ++kk)
        qf[kk] = *(const short8*)&Pb[(w * 16 + l15) * 136 + kk * 32 + quad * 8];

    floatx4 acc[4];
    #pragma unroll
    for (int dt = 0; dt < 4; ++dt) acc[dt] = floatx4{0.f, 0.f, 0.f, 0.f};
    float m_i = -1e30f, l_i = 0.f;

    // staging coords
    const int kr  = t >> 2, kc = (t & 3) * 16;    // K: row 0..127, col {0,16,32,48}
    const int vkv = (t & 63) * 2, vd = w * 8;     // V: kv pair, 8-d slab per wave

    // preload tile 0 into regs
    short8 kA = *(const short8*)&K[(size_t)kr * 64 + kc];
    short8 kB = *(const short8*)&K[(size_t)kr * 64 + kc + 8];
    short8 vA = *(const short8*)&V[(size_t)vkv * 64 + vd];
    short8 vB = *(const short8*)&V[(size_t)(vkv + 1) * 64 + vd];

    for (int kt = 0; kt < N_; kt += 128) {
        __syncthreads();   // prior tile's LDS reads complete
        // regs -> LDS
        *(short8*)&Ks[kr * 72 + kc]     = kA;
        *(short8*)&Ks[kr * 72 + kc + 8] = kB;
        #pragma unroll
        for (int j = 0; j < 8; ++j) {
            unsigned int pk = (unsigned int)(unsigned short)vA[j] |
                              ((unsigned int)(unsigned short)vB[j] << 16);
            *(unsigned int*)&Vt[(vd + j) * 136 + vkv] = pk;
        }
        __syncthreads();
        // prefetch next tile into regs — latency overlaps compute below
        if (kt + 128 < N_) {
            const int kt2 = kt + 128;
            kA = *(const short8*)&K[(size_t)(kt2 + kr) * 64 + kc];
            kB = *(const short8*)&K[(size_t)(kt2 + kr) * 64 + kc + 8];
            vA = *(const short8*)&V[(size_t)(kt2 + vkv) * 64 + vd];
            vB = *(const short8*)&V[(size_t)(kt2 + vkv + 1) * 64 + vd];
        }

        // S^T = K . Q^T : 8 row-tiles of 16 kv
        floatx4 sc[8];
        #pragma unroll
        for (int ct = 0; ct < 8; ++ct) {
            short8 a0 = *(const short8*)&Ks[(ct * 16 + l15) * 72 + quad * 8];
            short8 a1 = *(const short8*)&Ks[(ct * 16 + l15) * 72 + 32 + quad * 8];
            floatx4 r = {0.f, 0.f, 0.f, 0.f};
            r = __builtin_amdgcn_mfma_f32_16x16x32_bf16(a0, qf[0], r, 0, 0, 0);
            r = __builtin_amdgcn_mfma_f32_16x16x32_bf16(a1, qf[1], r, 0, 0, 0);
            sc[ct] = r;
        }

        // exp2-domain online softmax: lane owns q col (32 kv vals in regs)
        {
            float mx = m_i;
            #pragma unroll
            for (int ct = 0; ct < 8; ++ct)
                #pragma unroll
                for (int r = 0; r < 4; ++r) mx = fmaxf(mx, sc[ct][r]);
            mx = fmaxf(mx, __shfl_xor(mx, 16));
            mx = fmaxf(mx, __shfl_xor(mx, 32));
            float sum = 0.f;
            #pragma unroll
            for (int ct = 0; ct < 8; ++ct)
                #pragma unroll
                for (int r = 0; r < 4; ++r) {
                    const float p = __builtin_amdgcn_exp2f(sc[ct][r] - mx);
                    sc[ct][r] = p;
                    sum += p;
                }
            sum += __shfl_xor(sum, 16);
            sum += __shfl_xor(sum, 32);
            const float alpha = __builtin_amdgcn_exp2f(m_i - mx);
            l_i = l_i * alpha + sum;
            m_i = mx;
            #pragma unroll
            for (int dt = 0; dt < 4; ++dt) acc[dt] *= alpha;
            // write P row (own q row), packed uint2 (8B-aligned)
            const int prow = w * 16 + l15;
            #pragma unroll
            for (int ct = 0; ct < 8; ++ct) {
                uint2 pk;
                pk.x = pk2bf(sc[ct][0], sc[ct][1]);
                pk.y = pk2bf(sc[ct][2], sc[ct][3]);
                *(uint2*)&Pb[prow * 136 + ct * 16 + quad * 4] = pk;
            }
        }
        asm volatile("" ::: "memory");

        // O^T += V^T . P : A = Vt rows (d), B = own P row; K-dim 128 = 4 kk
        #pragma unroll
        for (int kk = 0; kk < 4; ++kk) {
            short8 pbf = *(const short8*)
                &Pb[(w * 16 + l15) * 136 + kk * 32 + quad * 8];
            #pragma unroll
            for (int dt = 0; dt < 4; ++dt) {
                short8 va = *(const short8*)
                    &Vt[(dt * 16 + l15) * 136 + kk * 32 + quad * 8];
                acc[dt] = __builtin_amdgcn_mfma_f32_16x16x32_bf16(
                    va, pbf, acc[dt], 0, 0, 0);
            }
        }
    }

    // epilogue: O^T regs -> Pb[q][d] (own row), then coalesced copy-out
    asm volatile("" ::: "memory");
    {
        const float inv = 1.0f / l_i;
        const int orow = w * 16 + l15;
        #pragma unroll
        for (int dt = 0; dt < 4; ++dt) {
            uint2 o2;
            o2.x = pk2bf(acc[dt][0] * inv, acc[dt][1] * inv);
            o2.y = pk2bf(acc[dt][2] * inv, acc[dt][3] * inv);
            *(uint2*)&Pb[orow * 136 + dt * 16 + quad * 4] = o2;
        }
    }
    __syncthreads();
    const int bidx = bh >> 4, h = bh & 15;
    {
        const int r = t >> 3, c = (t & 7) * 8;
        *(short8*)&ob[((size_t)(bidx * N_ + q0 + r)) * C_ + h * 64 + c] =
            *(const short8*)&Pb[r * 136 + c];
        *(short8*)&ob[((size_t)(bidx * N_ + q0 + r + 64)) * C_ + h * 64 + c] =
            *(const short8*)&Pb[(r + 64) * 136 + c];
    }
}

// ---------------------------------------------------------------------------
extern "C" void kernel_launch(void* const* d_in, const int* in_sizes, int n_in,
                              void* d_out, int out_size, void* d_ws, size_t ws_size,
                              hipStream_t stream) {
    const float* x      = (const float*)d_in[0];
    const float* W_qkv  = (const float*)d_in[1];
    const float* qn_w   = (const float*)d_in[2];
    const float* qn_b   = (const float*)d_in[3];
    const float* kn_w   = (const float*)d_in[4];
    const float* kn_b   = (const float*)d_in[5];
    const float* W_proj = (const float*)d_in[6];
    const float* b_proj = (const float*)d_in[7];
    float* out = (float*)d_out;

    unsigned short* qb  = (unsigned short*)d_ws;               // 3 x QSZ bf16
    unsigned short* kb  = qb + (size_t)QSZ;
    unsigned short* vb  = kb + (size_t)QSZ;
    unsigned short* ob  = vb + (size_t)QSZ;                    // [B,N,C] bf16
    unsigned short* xb  = ob + (size_t)B_ * N_ * C_;           // [4096][1024]
    unsigned short* wqt = xb + (size_t)B_ * N_ * C_;           // [3072][1024]
    unsigned short* wpt = wqt + (size_t)3 * C_ * C_;           // [1024][1024]

    pack_bf16_kernel<<<dim3((B_ * N_ * C_) / 1024), 256, 0, stream>>>(x, xb);
    transpose_pack_kernel<<<dim3(96, 32), 256, 0, stream>>>(W_qkv, wqt, 1024, 3072);
    transpose_pack_kernel<<<dim3(32, 32), 256, 0, stream>>>(W_proj, wpt, 1024, 1024);
    gemm_qkv_kernel<<<dim3(24, 32), 256, 0, stream>>>(xb, wqt, qb, kb, vb);
    ln_kernel<<<dim3((B_ * H_ * N_) / 4, 2), 256, 0, stream>>>(qb, kb, qn_w, qn_b, kn_w, kn_b);
    flash_kernel<<<dim3(N_ / 128, B_ * H_), 512, 0, stream>>>(qb, kb, vb, ob);
    gemm_proj_kernel<<<dim3(8, 32), 256, 0, stream>>>(ob, wpt, b_proj, out);
}

// Round 7
// 204.742 us; speedup vs baseline: 6.5014x; 1.1057x over previous
//
#include <hip/hip_runtime.h>
#include <hip/hip_bf16.h>

#define B_  2
#define N_  2048
#define C_  1024
#define H_  16
#define HD_ 64
#define QSZ (B_*N_*C_)       // elements per q/k/v buffer
#define QSCALE 0.18033688011112042f   // 0.125 * log2(e): softmax in exp2 domain

typedef __attribute__((ext_vector_type(8))) short short8;            // 8 bf16
typedef __attribute__((ext_vector_type(4))) float floatx4;
typedef __attribute__((ext_vector_type(4))) unsigned short ushort4v; // 4 bf16

__device__ __forceinline__ unsigned short f2bf(float f) {
    unsigned int u = __builtin_bit_cast(unsigned int, f);
    u += 0x7fff + ((u >> 16) & 1);          // round-to-nearest-even
    return (unsigned short)(u >> 16);
}
__device__ __forceinline__ float bf2f(unsigned short h) {
    return __builtin_bit_cast(float, (unsigned int)h << 16);
}
// pack two fp32 -> two RNE bf16 in one u32 (lo = a, hi = b) via v_perm_b32
__device__ __forceinline__ unsigned int pk2bf(float a, float b) {
    unsigned int ua = __builtin_bit_cast(unsigned int, a);
    unsigned int ub = __builtin_bit_cast(unsigned int, b);
    ua += 0x7fff + ((ua >> 16) & 1);
    ub += 0x7fff + ((ub >> 16) & 1);
    return __builtin_amdgcn_perm(ub, ua, 0x07060302);
}

// async global->LDS, 16 B per lane; LDS dest = wave-uniform base + lane*16
__device__ __forceinline__ void g2l16(const void* g, void* l) {
    __builtin_amdgcn_global_load_lds(
        (const __attribute__((address_space(1))) void*)g,
        (__attribute__((address_space(3))) void*)l, 16, 0, 0);
}

// ---------------------------------------------------------------------------
// pack fp32 -> bf16, same layout
// ---------------------------------------------------------------------------
__global__ __launch_bounds__(256) void pack_bf16_kernel(
    const float* __restrict__ src, unsigned short* __restrict__ dst)
{
    const int i = blockIdx.x * 256 + threadIdx.x;
    float4 v = ((const float4*)src)[i];
    ushort4 o = {f2bf(v.x), f2bf(v.y), f2bf(v.z), f2bf(v.w)};
    ((ushort4*)dst)[i] = o;
}

// ---------------------------------------------------------------------------
// transpose + pack: W fp32 [Kd][Nd] -> Wt bf16 [Nd][Kd]
// ---------------------------------------------------------------------------
__global__ __launch_bounds__(256) void transpose_pack_kernel(
    const float* __restrict__ W, unsigned short* __restrict__ Wt,
    int Kd, int Nd)
{
    __shared__ unsigned short tl[32][34];
    const int r  = threadIdx.x >> 3;
    const int c4 = (threadIdx.x & 7) * 4;
    const int n0 = blockIdx.x * 32, k0 = blockIdx.y * 32;
    float4 v = *(const float4*)&W[(size_t)(k0 + r) * Nd + n0 + c4];
    tl[r][c4 + 0] = f2bf(v.x); tl[r][c4 + 1] = f2bf(v.y);
    tl[r][c4 + 2] = f2bf(v.z); tl[r][c4 + 3] = f2bf(v.w);
    __syncthreads();
    ushort4 o = {tl[c4 + 0][r], tl[c4 + 1][r], tl[c4 + 2][r], tl[c4 + 3][r]};
    *(ushort4*)&Wt[(size_t)(n0 + r) * Kd + k0 + c4] = o;
}

// ---------------------------------------------------------------------------
// bf16 MFMA GEMM core (m97 structure): 128x128 tile, BK=32, 4 waves
// ---------------------------------------------------------------------------
#define GEMM_CORE(A_, Bt_, Kd_, row0_, col0_)                                 \
    __shared__ unsigned short As[128 * 32];                                   \
    __shared__ unsigned short Bs[128 * 32];                                   \
    const int t    = threadIdx.x;                                             \
    const int lane = t & 63;                                                  \
    const int w    = t >> 6;                                                  \
    const int l15  = lane & 15;                                               \
    const int quad = lane >> 4;                                               \
    const int wm   = w >> 1, wn = w & 1;                                      \
    size_t aOff = (size_t)(row0_ + w * 16 + (lane >> 2)) * Kd_ + (lane & 3) * 8; \
    size_t bOff = (size_t)(col0_ + w * 16 + (lane >> 2)) * Kd_ + (lane & 3) * 8; \
    floatx4 acc[4][4];                                                        \
    _Pragma("unroll")                                                         \
    for (int i = 0; i < 4; ++i)                                               \
        _Pragma("unroll")                                                     \
        for (int j = 0; j < 4; ++j) acc[i][j] = floatx4{0.f, 0.f, 0.f, 0.f};  \
    for (int k0 = 0; k0 < Kd_; k0 += 32) {                                    \
        _Pragma("unroll")                                                     \
        for (int c = 0; c < 2; ++c) {                                         \
            g2l16(&A_[aOff + (size_t)c * 64 * Kd_ + k0],                      \
                  &As[(w * 16 + c * 64) * 32]);                               \
            g2l16(&Bt_[bOff + (size_t)c * 64 * Kd_ + k0],                     \
                  &Bs[(w * 16 + c * 64) * 32]);                               \
        }                                                                     \
        __syncthreads();                                                      \
        short8 af[4], bf[4];                                                  \
        _Pragma("unroll")                                                     \
        for (int i = 0; i < 4; ++i)                                           \
            af[i] = *(const short8*)&As[(wm * 64 + i * 16 + l15) * 32 + quad * 8]; \
        _Pragma("unroll")                                                     \
        for (int j = 0; j < 4; ++j)                                           \
            bf[j] = *(const short8*)&Bs[(wn * 64 + j * 16 + l15) * 32 + quad * 8]; \
        _Pragma("unroll")                                                     \
        for (int i = 0; i < 4; ++i)                                           \
            _Pragma("unroll")                                                 \
            for (int j = 0; j < 4; ++j)                                       \
                acc[i][j] = __builtin_amdgcn_mfma_f32_16x16x32_bf16(          \
                    af[i], bf[j], acc[i][j], 0, 0, 0);                        \
        __syncthreads();                                                      \
    }

// ---------------------------------------------------------------------------
// Kernel 1: qkv = x @ W_qkv with FUSED per-head LayerNorm on q,k (fp32 math
// on accumulators, before bf16 rounding). q scaled by 0.125*log2(e).
// Each wave's 64-col chunk lies in exactly one head; LN reduction over d =
// 4 in-lane adds + 4 shuffles within the 16-lane l15 group.
// ---------------------------------------------------------------------------
__global__ __launch_bounds__(256) void gemm_qkv_kernel(
    const unsigned short* __restrict__ X,    // [4096][1024] bf16
    const unsigned short* __restrict__ Wt,   // [3072][1024] bf16 (W^T)
    const float* __restrict__ qn_w, const float* __restrict__ qn_b,
    const float* __restrict__ kn_w, const float* __restrict__ kn_b,
    unsigned short* __restrict__ qb, unsigned short* __restrict__ kb,
    unsigned short* __restrict__ vb)
{
    const int row0 = blockIdx.y * 128;
    const int col0 = blockIdx.x * 128;
    GEMM_CORE(X, Wt, 1024, row0, col0)
    const int which = col0 >> 10;            // 0=q 1=k 2=v, uniform per block
    const int h = ((col0 & 1023) >> 6) + wn; // head index for this wave
    if (which == 2) {
        #pragma unroll
        for (int j = 0; j < 4; ++j) {
            const int d = j * 16 + l15;
            #pragma unroll
            for (int i = 0; i < 4; ++i) {
                #pragma unroll
                for (int r = 0; r < 4; ++r) {
                    const int grow = row0 + wm * 64 + i * 16 + quad * 4 + r;
                    const int bidx = grow >> 11, n = grow & 2047;
                    vb[(((size_t)(bidx * H_ + h) * N_ + n) * HD_) + d] =
                        f2bf(acc[i][j][r]);
                }
            }
        }
    } else {
        const float* wt = (which == 0) ? qn_w : kn_w;
        const float* bi = (which == 0) ? qn_b : kn_b;
        unsigned short* dstbuf = (which == 0) ? qb : kb;
        float w4[4], b4[4];
        #pragma unroll
        for (int j = 0; j < 4; ++j) {
            w4[j] = wt[j * 16 + l15];
            b4[j] = bi[j * 16 + l15];
        }
        #pragma unroll
        for (int i = 0; i < 4; ++i) {
            #pragma unroll
            for (int r = 0; r < 4; ++r) {
                float v0 = acc[i][0][r], v1 = acc[i][1][r],
                      v2 = acc[i][2][r], v3 = acc[i][3][r];
                float s = (v0 + v1) + (v2 + v3);
                #pragma unroll
                for (int o = 1; o < 16; o <<= 1) s += __shfl_xor(s, o);
                const float mu = s * (1.0f / 64.0f);
                const float d0 = v0 - mu, d1 = v1 - mu,
                            d2 = v2 - mu, d3 = v3 - mu;
                float s2 = (d0 * d0 + d1 * d1) + (d2 * d2 + d3 * d3);
                #pragma unroll
                for (int o = 1; o < 16; o <<= 1) s2 += __shfl_xor(s2, o);
                const float rstd = rsqrtf(s2 * (1.0f / 64.0f) + 1e-5f);
                float y0 = d0 * rstd * w4[0] + b4[0];
                float y1 = d1 * rstd * w4[1] + b4[1];
                float y2 = d2 * rstd * w4[2] + b4[2];
                float y3 = d3 * rstd * w4[3] + b4[3];
                if (which == 0) {
                    y0 *= QSCALE; y1 *= QSCALE; y2 *= QSCALE; y3 *= QSCALE;
                }
                const int grow = row0 + wm * 64 + i * 16 + quad * 4 + r;
                const int bidx = grow >> 11, n = grow & 2047;
                unsigned short* dp =
                    &dstbuf[(((size_t)(bidx * H_ + h) * N_ + n) * HD_) + l15];
                dp[0]  = f2bf(y0);
                dp[16] = f2bf(y1);
                dp[32] = f2bf(y2);
                dp[48] = f2bf(y3);
            }
        }
    }
}

__global__ __launch_bounds__(256) void gemm_proj_kernel(
    const unsigned short* __restrict__ O,    // [4096][1024] bf16
    const unsigned short* __restrict__ Wt,   // [1024][1024] bf16 (W^T)
    const float* __restrict__ bias, float* __restrict__ out)
{
    const int row0 = blockIdx.y * 128;
    const int col0 = blockIdx.x * 128;
    GEMM_CORE(O, Wt, 1024, row0, col0)
    #pragma unroll
    for (int j = 0; j < 4; ++j) {
        const int gcol = col0 + wn * 64 + j * 16 + l15;
        const float b = bias[gcol];
        #pragma unroll
        for (int i = 0; i < 4; ++i) {
            #pragma unroll
            for (int r = 0; r < 4; ++r) {
                const int grow = row0 + wm * 64 + i * 16 + quad * 4 + r;
                out[(size_t)grow * 1024 + gcol] = acc[i][j][r] + b;
            }
        }
    }
}

// ---------------------------------------------------------------------------
// Kernel 3: flash attention v5 — fixed-reference exp2 softmax (no online
// max: LN-bounded logits, |s| << 127 so exp2(s) cannot overflow; the final
// division normalizes exactly). Software-pipelined, 128-kv tiles.
// Block = 512 thr = 8 waves; Q-tile 128 (16 rows/wave).
// ---------------------------------------------------------------------------
__global__ __launch_bounds__(512, 4) void flash_kernel(
    const unsigned short* __restrict__ qb, const unsigned short* __restrict__ kb,
    const unsigned short* __restrict__ vb, unsigned short* __restrict__ ob)
{
    __shared__ __align__(16) unsigned short Ks[128 * 72];
    __shared__ __align__(16) unsigned short Vt[64 * 136];    // [d][kv]
    __shared__ __align__(16) unsigned short Pb[128 * 136];   // Q stage -> P -> O
    const int t    = threadIdx.x;
    const int lane = t & 63;
    const int w    = t >> 6;                 // wave 0..7, owns q rows 16w..16w+15
    const int l15  = lane & 15;
    const int quad = lane >> 4;
    const int q0   = blockIdx.x * 128;
    const int bh   = blockIdx.y;
    const unsigned short* Q = qb + (size_t)bh * N_ * HD_;
    const unsigned short* K = kb + (size_t)bh * N_ * HD_;
    const unsigned short* V = vb + (size_t)bh * N_ * HD_;

    // stage Q (128x64) into Pb
    {
        const int r = t >> 3, c = (t & 7) * 8;
        *(short8*)&Pb[r * 136 + c] =
            *(const short8*)&Q[(size_t)(q0 + r) * 64 + c];
        *(short8*)&Pb[(r + 64) * 136 + c] =
            *(const short8*)&Q[(size_t)(q0 + r + 64) * 64 + c];
    }
    __syncthreads();
    // Q fragment (B-operand): own row 16w + l15
    short8 qf[2];
    #pragma unroll
    for (int kk = 0; kk < 2; ++kk)
        qf[kk] = *(const short8*)&Pb[(w * 16 + l15) * 136 + kk * 32 + quad * 8];

    floatx4 acc[4];
    #pragma unroll
    for (int dt = 0; dt < 4; ++dt) acc[dt] = floatx4{0.f, 0.f, 0.f, 0.f};
    float l_part = 0.f;   // per-lane partial softmax denominator

    // staging coords
    const int kr  = t >> 2, kc = (t & 3) * 16;    // K: row 0..127, col {0,16,32,48}
    const int vkv = (t & 63) * 2, vd = w * 8;     // V: kv pair, 8-d slab per wave

    // preload tile 0 into regs
    short8 kA = *(const short8*)&K[(size_t)kr * 64 + kc];
    short8 kB = *(const short8*)&K[(size_t)kr * 64 + kc + 8];
    short8 vA = *(const short8*)&V[(size_t)vkv * 64 + vd];
    short8 vB = *(const short8*)&V[(size_t)(vkv + 1) * 64 + vd];

    for (int kt = 0; kt < N_; kt += 128) {
        __syncthreads();   // prior tile's LDS reads complete
        // regs -> LDS
        *(short8*)&Ks[kr * 72 + kc]     = kA;
        *(short8*)&Ks[kr * 72 + kc + 8] = kB;
        #pragma unroll
        for (int j = 0; j < 8; ++j) {
            unsigned int pk = (unsigned int)(unsigned short)vA[j] |
                              ((unsigned int)(unsigned short)vB[j] << 16);
            *(unsigned int*)&Vt[(vd + j) * 136 + vkv] = pk;
        }
        __syncthreads();
        // prefetch next tile into regs — latency overlaps compute below
        if (kt + 128 < N_) {
            const int kt2 = kt + 128;
            kA = *(const short8*)&K[(size_t)(kt2 + kr) * 64 + kc];
            kB = *(const short8*)&K[(size_t)(kt2 + kr) * 64 + kc + 8];
            vA = *(const short8*)&V[(size_t)(kt2 + vkv) * 64 + vd];
            vB = *(const short8*)&V[(size_t)(kt2 + vkv + 1) * 64 + vd];
        }

        // S^T = K . Q^T : 8 row-tiles of 16 kv
        floatx4 sc[8];
        #pragma unroll
        for (int ct = 0; ct < 8; ++ct) {
            short8 a0 = *(const short8*)&Ks[(ct * 16 + l15) * 72 + quad * 8];
            short8 a1 = *(const short8*)&Ks[(ct * 16 + l15) * 72 + 32 + quad * 8];
            floatx4 r = {0.f, 0.f, 0.f, 0.f};
            r = __builtin_amdgcn_mfma_f32_16x16x32_bf16(a0, qf[0], r, 0, 0, 0);
            r = __builtin_amdgcn_mfma_f32_16x16x32_bf16(a1, qf[1], r, 0, 0, 0);
            sc[ct] = r;
        }

        // fixed-reference softmax: p = exp2(s) directly, defer the sum
        const int prow = w * 16 + l15;
        #pragma unroll
        for (int ct = 0; ct < 8; ++ct) {
            float p0 = __builtin_amdgcn_exp2f(sc[ct][0]);
            float p1 = __builtin_amdgcn_exp2f(sc[ct][1]);
            float p2 = __builtin_amdgcn_exp2f(sc[ct][2]);
            float p3 = __builtin_amdgcn_exp2f(sc[ct][3]);
            l_part += (p0 + p1) + (p2 + p3);
            uint2 pk;
            pk.x = pk2bf(p0, p1);
            pk.y = pk2bf(p2, p3);
            *(uint2*)&Pb[prow * 136 + ct * 16 + quad * 4] = pk;
        }
        asm volatile("" ::: "memory");

        // O^T += V^T . P : A = Vt rows (d), B = own P row; K-dim 128 = 4 kk
        #pragma unroll
        for (int kk = 0; kk < 4; ++kk) {
            short8 pbf = *(const short8*)
                &Pb[(w * 16 + l15) * 136 + kk * 32 + quad * 8];
            #pragma unroll
            for (int dt = 0; dt < 4; ++dt) {
                short8 va = *(const short8*)
                    &Vt[(dt * 16 + l15) * 136 + kk * 32 + quad * 8];
                acc[dt] = __builtin_amdgcn_mfma_f32_16x16x32_bf16(
                    va, pbf, acc[dt], 0, 0, 0);
            }
        }
    }

    // denominator: reduce partial sums across the 4 quads holding this q col
    l_part += __shfl_xor(l_part, 16);
    l_part += __shfl_xor(l_part, 32);

    // epilogue: O^T regs -> Pb[q][d] (own row), then coalesced copy-out
    asm volatile("" ::: "memory");
    {
        const float inv = 1.0f / l_part;
        const int orow = w * 16 + l15;
        #pragma unroll
        for (int dt = 0; dt < 4; ++dt) {
            uint2 o2;
            o2.x = pk2bf(acc[dt][0] * inv, acc[dt][1] * inv);
            o2.y = pk2bf(acc[dt][2] * inv, acc[dt][3] * inv);
            *(uint2*)&Pb[orow * 136 + dt * 16 + quad * 4] = o2;
        }
    }
    __syncthreads();
    const int bidx = bh >> 4, h = bh & 15;
    {
        const int r = t >> 3, c = (t & 7) * 8;
        *(short8*)&ob[((size_t)(bidx * N_ + q0 + r)) * C_ + h * 64 + c] =
            *(const short8*)&Pb[r * 136 + c];
        *(short8*)&ob[((size_t)(bidx * N_ + q0 + r + 64)) * C_ + h * 64 + c] =
            *(const short8*)&Pb[(r + 64) * 136 + c];
    }
}

// ---------------------------------------------------------------------------
extern "C" void kernel_launch(void* const* d_in, const int* in_sizes, int n_in,
                              void* d_out, int out_size, void* d_ws, size_t ws_size,
                              hipStream_t stream) {
    const float* x      = (const float*)d_in[0];
    const float* W_qkv  = (const float*)d_in[1];
    const float* qn_w   = (const float*)d_in[2];
    const float* qn_b   = (const float*)d_in[3];
    const float* kn_w   = (const float*)d_in[4];
    const float* kn_b   = (const float*)d_in[5];
    const float* W_proj = (const float*)d_in[6];
    const float* b_proj = (const float*)d_in[7];
    float* out = (float*)d_out;

    unsigned short* qb  = (unsigned short*)d_ws;               // 3 x QSZ bf16
    unsigned short* kb  = qb + (size_t)QSZ;
    unsigned short* vb  = kb + (size_t)QSZ;
    unsigned short* ob  = vb + (size_t)QSZ;                    // [B,N,C] bf16
    unsigned short* xb  = ob + (size_t)B_ * N_ * C_;           // [4096][1024]
    unsigned short* wqt = xb + (size_t)B_ * N_ * C_;           // [3072][1024]
    unsigned short* wpt = wqt + (size_t)3 * C_ * C_;           // [1024][1024]

    pack_bf16_kernel<<<dim3((B_ * N_ * C_) / 1024), 256, 0, stream>>>(x, xb);
    transpose_pack_kernel<<<dim3(96, 32), 256, 0, stream>>>(W_qkv, wqt, 1024, 3072);
    transpose_pack_kernel<<<dim3(32, 32), 256, 0, stream>>>(W_proj, wpt, 1024, 1024);
    // qkv GEMM with fused LN(q,k) + q-scale
    gemm_qkv_kernel<<<dim3(24, 32), 256, 0, stream>>>(
        xb, wqt, qn_w, qn_b, kn_w, kn_b, qb, kb, vb);
    flash_kernel<<<dim3(N_ / 128, B_ * H_), 512, 0, stream>>>(qb, kb, vb, ob);
    gemm_proj_kernel<<<dim3(8, 32), 256, 0, stream>>>(ob, wpt, b_proj, out);
}

// Round 9
// 202.892 us; speedup vs baseline: 6.5607x; 1.0091x over previous
//
#include <hip/hip_runtime.h>
#include <hip/hip_bf16.h>

#define B_  2
#define N_  2048
#define C_  1024
#define H_  16
#define HD_ 64
#define QSZ (B_*N_*C_)       // elements per q/k/v buffer
#define QSCALE 0.18033688011112042f   // 0.125 * log2(e): softmax in exp2 domain

typedef __attribute__((ext_vector_type(8))) short short8;            // 8 bf16
typedef __attribute__((ext_vector_type(4))) float floatx4;
typedef __attribute__((ext_vector_type(4))) unsigned short ushort4v; // 4 bf16

__device__ __forceinline__ unsigned short f2bf(float f) {
    unsigned int u = __builtin_bit_cast(unsigned int, f);
    u += 0x7fff + ((u >> 16) & 1);          // round-to-nearest-even
    return (unsigned short)(u >> 16);
}
__device__ __forceinline__ float bf2f(unsigned short h) {
    return __builtin_bit_cast(float, (unsigned int)h << 16);
}
// pack two fp32 -> two RNE bf16 in one u32 (lo = a, hi = b) via v_perm_b32
__device__ __forceinline__ unsigned int pk2bf(float a, float b) {
    unsigned int ua = __builtin_bit_cast(unsigned int, a);
    unsigned int ub = __builtin_bit_cast(unsigned int, b);
    ua += 0x7fff + ((ua >> 16) & 1);
    ub += 0x7fff + ((ub >> 16) & 1);
    return __builtin_amdgcn_perm(ub, ua, 0x07060302);
}

// async global->LDS, 16 B per lane; LDS dest = wave-uniform base + lane*16
__device__ __forceinline__ void g2l16(const void* g, void* l) {
    __builtin_amdgcn_global_load_lds(
        (const __attribute__((address_space(1))) void*)g,
        (__attribute__((address_space(3))) void*)l, 16, 0, 0);
}

// ---------------------------------------------------------------------------
// pack fp32 -> bf16, same layout
// ---------------------------------------------------------------------------
__global__ __launch_bounds__(256) void pack_bf16_kernel(
    const float* __restrict__ src, unsigned short* __restrict__ dst)
{
    const int i = blockIdx.x * 256 + threadIdx.x;
    float4 v = ((const float4*)src)[i];
    ushort4 o = {f2bf(v.x), f2bf(v.y), f2bf(v.z), f2bf(v.w)};
    ((ushort4*)dst)[i] = o;
}

// ---------------------------------------------------------------------------
// transpose + pack BOTH weights in one launch:
// bx < 96: W_qkv [1024][3072] -> wqt [3072][1024]
// bx >= 96: W_proj [1024][1024] -> wpt [1024][1024]
// ---------------------------------------------------------------------------
__global__ __launch_bounds__(256) void transpose_pack2_kernel(
    const float* __restrict__ Wq, unsigned short* __restrict__ Wqt,
    const float* __restrict__ Wp, unsigned short* __restrict__ Wpt)
{
    __shared__ unsigned short tl[32][34];
    const bool isq = blockIdx.x < 96;
    const int bx = isq ? blockIdx.x : blockIdx.x - 96;
    const int Nd = isq ? 3072 : 1024;
    const float* W = isq ? Wq : Wp;
    unsigned short* Wt = isq ? Wqt : Wpt;
    const int r  = threadIdx.x >> 3;
    const int c4 = (threadIdx.x & 7) * 4;
    const int n0 = bx * 32, k0 = blockIdx.y * 32;
    float4 v = *(const float4*)&W[(size_t)(k0 + r) * Nd + n0 + c4];
    tl[r][c4 + 0] = f2bf(v.x); tl[r][c4 + 1] = f2bf(v.y);
    tl[r][c4 + 2] = f2bf(v.z); tl[r][c4 + 3] = f2bf(v.w);
    __syncthreads();
    ushort4 o = {tl[c4 + 0][r], tl[c4 + 1][r], tl[c4 + 2][r], tl[c4 + 3][r]};
    *(ushort4*)&Wt[(size_t)(n0 + r) * 1024 + k0 + c4] = o;
}

// ---------------------------------------------------------------------------
// bf16 MFMA GEMM core (m97 structure): 128x128 tile, BK=32, 4 waves
// ---------------------------------------------------------------------------
#define GEMM_CORE(A_, Bt_, Kd_, row0_, col0_)                                 \
    __shared__ unsigned short As[128 * 32];                                   \
    __shared__ unsigned short Bs[128 * 32];                                   \
    const int t    = threadIdx.x;                                             \
    const int lane = t & 63;                                                  \
    const int w    = t >> 6;                                                  \
    const int l15  = lane & 15;                                               \
    const int quad = lane >> 4;                                               \
    const int wm   = w >> 1, wn = w & 1;                                      \
    size_t aOff = (size_t)(row0_ + w * 16 + (lane >> 2)) * Kd_ + (lane & 3) * 8; \
    size_t bOff = (size_t)(col0_ + w * 16 + (lane >> 2)) * Kd_ + (lane & 3) * 8; \
    floatx4 acc[4][4];                                                        \
    _Pragma("unroll")                                                         \
    for (int i = 0; i < 4; ++i)                                               \
        _Pragma("unroll")                                                     \
        for (int j = 0; j < 4; ++j) acc[i][j] = floatx4{0.f, 0.f, 0.f, 0.f};  \
    for (int k0 = 0; k0 < Kd_; k0 += 32) {                                    \
        _Pragma("unroll")                                                     \
        for (int c = 0; c < 2; ++c) {                                         \
            g2l16(&A_[aOff + (size_t)c * 64 * Kd_ + k0],                      \
                  &As[(w * 16 + c * 64) * 32]);                               \
            g2l16(&Bt_[bOff + (size_t)c * 64 * Kd_ + k0],                     \
                  &Bs[(w * 16 + c * 64) * 32]);                               \
        }                                                                     \
        __syncthreads();                                                      \
        short8 af[4], bf[4];                                                  \
        _Pragma("unroll")                                                     \
        for (int i = 0; i < 4; ++i)                                           \
            af[i] = *(const short8*)&As[(wm * 64 + i * 16 + l15) * 32 + quad * 8]; \
        _Pragma("unroll")                                                     \
        for (int j = 0; j < 4; ++j)                                           \
            bf[j] = *(const short8*)&Bs[(wn * 64 + j * 16 + l15) * 32 + quad * 8]; \
        _Pragma("unroll")                                                     \
        for (int i = 0; i < 4; ++i)                                           \
            _Pragma("unroll")                                                 \
            for (int j = 0; j < 4; ++j)                                       \
                acc[i][j] = __builtin_amdgcn_mfma_f32_16x16x32_bf16(          \
                    af[i], bf[j], acc[i][j], 0, 0, 0);                        \
        __syncthreads();                                                      \
    }

// ---------------------------------------------------------------------------
// Kernel 1: qkv = x @ W_qkv with FUSED per-head LayerNorm on q,k (fp32 math
// on accumulators, before bf16 rounding). q scaled by 0.125*log2(e).
// ---------------------------------------------------------------------------
__global__ __launch_bounds__(256) void gemm_qkv_kernel(
    const unsigned short* __restrict__ X,    // [4096][1024] bf16
    const unsigned short* __restrict__ Wt,   // [3072][1024] bf16 (W^T)
    const float* __restrict__ qn_w, const float* __restrict__ qn_b,
    const float* __restrict__ kn_w, const float* __restrict__ kn_b,
    unsigned short* __restrict__ qb, unsigned short* __restrict__ kb,
    unsigned short* __restrict__ vb)
{
    const int row0 = blockIdx.y * 128;
    const int col0 = blockIdx.x * 128;
    GEMM_CORE(X, Wt, 1024, row0, col0)
    const int which = col0 >> 10;            // 0=q 1=k 2=v, uniform per block
    const int h = ((col0 & 1023) >> 6) + wn; // head index for this wave
    if (which == 2) {
        #pragma unroll
        for (int j = 0; j < 4; ++j) {
            const int d = j * 16 + l15;
            #pragma unroll
            for (int i = 0; i < 4; ++i) {
                #pragma unroll
                for (int r = 0; r < 4; ++r) {
                    const int grow = row0 + wm * 64 + i * 16 + quad * 4 + r;
                    const int bidx = grow >> 11, n = grow & 2047;
                    vb[(((size_t)(bidx * H_ + h) * N_ + n) * HD_) + d] =
                        f2bf(acc[i][j][r]);
                }
            }
        }
    } else {
        const float* wt = (which == 0) ? qn_w : kn_w;
        const float* bi = (which == 0) ? qn_b : kn_b;
        unsigned short* dstbuf = (which == 0) ? qb : kb;
        float w4[4], b4[4];
        #pragma unroll
        for (int j = 0; j < 4; ++j) {
            w4[j] = wt[j * 16 + l15];
            b4[j] = bi[j * 16 + l15];
        }
        #pragma unroll
        for (int i = 0; i < 4; ++i) {
            #pragma unroll
            for (int r = 0; r < 4; ++r) {
                float v0 = acc[i][0][r], v1 = acc[i][1][r],
                      v2 = acc[i][2][r], v3 = acc[i][3][r];
                float s = (v0 + v1) + (v2 + v3);
                #pragma unroll
                for (int o = 1; o < 16; o <<= 1) s += __shfl_xor(s, o);
                const float mu = s * (1.0f / 64.0f);
                const float d0 = v0 - mu, d1 = v1 - mu,
                            d2 = v2 - mu, d3 = v3 - mu;
                float s2 = (d0 * d0 + d1 * d1) + (d2 * d2 + d3 * d3);
                #pragma unroll
                for (int o = 1; o < 16; o <<= 1) s2 += __shfl_xor(s2, o);
                const float rstd = rsqrtf(s2 * (1.0f / 64.0f) + 1e-5f);
                float y0 = d0 * rstd * w4[0] + b4[0];
                float y1 = d1 * rstd * w4[1] + b4[1];
                float y2 = d2 * rstd * w4[2] + b4[2];
                float y3 = d3 * rstd * w4[3] + b4[3];
                if (which == 0) {
                    y0 *= QSCALE; y1 *= QSCALE; y2 *= QSCALE; y3 *= QSCALE;
                }
                const int grow = row0 + wm * 64 + i * 16 + quad * 4 + r;
                const int bidx = grow >> 11, n = grow & 2047;
                unsigned short* dp =
                    &dstbuf[(((size_t)(bidx * H_ + h) * N_ + n) * HD_) + l15];
                dp[0]  = f2bf(y0);
                dp[16] = f2bf(y1);
                dp[32] = f2bf(y2);
                dp[48] = f2bf(y3);
            }
        }
    }
}

// ---------------------------------------------------------------------------
// Kernel 4: out = o @ W_proj + b_proj. 64x128 tile (512 blocks = 2/CU).
// 4 waves: all share rows 0..63 (4 i-frags); wave w owns cols 32w..32w+31.
// ---------------------------------------------------------------------------
__global__ __launch_bounds__(256) void gemm_proj_kernel(
    const unsigned short* __restrict__ O,    // [4096][1024] bf16
    const unsigned short* __restrict__ Wt,   // [1024][1024] bf16 (W^T)
    const float* __restrict__ bias, float* __restrict__ out)
{
    __shared__ unsigned short As[64 * 32];
    __shared__ unsigned short Bs[128 * 32];
    const int t    = threadIdx.x;
    const int lane = t & 63;
    const int w    = t >> 6;
    const int l15  = lane & 15;
    const int quad = lane >> 4;
    const int row0 = blockIdx.y * 64;
    const int col0 = blockIdx.x * 128;
    size_t aOff = (size_t)(row0 + w * 16 + (lane >> 2)) * 1024 + (lane & 3) * 8;
    size_t bOff = (size_t)(col0 + w * 16 + (lane >> 2)) * 1024 + (lane & 3) * 8;
    floatx4 acc[4][2];
    #pragma unroll
    for (int i = 0; i < 4; ++i)
        #pragma unroll
        for (int j = 0; j < 2; ++j) acc[i][j] = floatx4{0.f, 0.f, 0.f, 0.f};
    for (int k0 = 0; k0 < 1024; k0 += 32) {
        g2l16(&O[aOff + k0], &As[(w * 16) * 32]);
        #pragma unroll
        for (int c = 0; c < 2; ++c)
            g2l16(&Wt[bOff + (size_t)c * 64 * 1024 + k0],
                  &Bs[(w * 16 + c * 64) * 32]);
        __syncthreads();
        short8 af[4], bf[2];
        #pragma unroll
        for (int i = 0; i < 4; ++i)
            af[i] = *(const short8*)&As[(i * 16 + l15) * 32 + quad * 8];
        #pragma unroll
        for (int j = 0; j < 2; ++j)
            bf[j] = *(const short8*)&Bs[(w * 32 + j * 16 + l15) * 32 + quad * 8];
        #pragma unroll
        for (int i = 0; i < 4; ++i)
            #pragma unroll
            for (int j = 0; j < 2; ++j)
                acc[i][j] = __builtin_amdgcn_mfma_f32_16x16x32_bf16(
                    af[i], bf[j], acc[i][j], 0, 0, 0);
        __syncthreads();
    }
    #pragma unroll
    for (int j = 0; j < 2; ++j) {
        const int gcol = col0 + w * 32 + j * 16 + l15;
        const float b = bias[gcol];
        #pragma unroll
        for (int i = 0; i < 4; ++i) {
            #pragma unroll
            for (int r = 0; r < 4; ++r) {
                const int grow = row0 + i * 16 + quad * 4 + r;
                out[(size_t)grow * 1024 + gcol] = acc[i][j][r] + b;
            }
        }
    }
}

// ---------------------------------------------------------------------------
// Kernel 3: flash attention v6b — 4 waves x 32 q-rows (2 groups of 16).
// Each K/Vt A-fragment read feeds TWO MFMAs (both q-groups): per-block LDS
// A-traffic halves vs v5. Fixed-reference exp2 softmax, software-pipelined,
// kv-tile 128. Block 256 thr, LDS 70.6 KB -> 2 blocks/CU.
// FIX vs v8: K staging now covers the full 32-col span per thread
// (kR[0..3] at kc+0/8/16/24) — v8 left cols 16-31,48-63 unwritten -> NaN.
// ---------------------------------------------------------------------------
__global__ __launch_bounds__(256, 2) void flash_kernel(
    const unsigned short* __restrict__ qb, const unsigned short* __restrict__ kb,
    const unsigned short* __restrict__ vb, unsigned short* __restrict__ ob)
{
    __shared__ __align__(16) unsigned short Ks[128 * 72];
    __shared__ __align__(16) unsigned short Vt[64 * 136];    // [d][kv]
    __shared__ __align__(16) unsigned short Pb[128 * 136];   // Q stage -> P -> O
    const int t    = threadIdx.x;
    const int lane = t & 63;
    const int w    = t >> 6;                 // wave 0..3
    const int l15  = lane & 15;
    const int quad = lane >> 4;
    const int q0   = blockIdx.x * 128;
    const int bh   = blockIdx.y;
    const unsigned short* Q = qb + (size_t)bh * N_ * HD_;
    const unsigned short* K = kb + (size_t)bh * N_ * HD_;
    const unsigned short* V = vb + (size_t)bh * N_ * HD_;

    // stage Q (128x64) into Pb: 256 thr x 4 reps
    {
        const int r = t >> 3, c = (t & 7) * 8;
        #pragma unroll
        for (int rep = 0; rep < 4; ++rep)
            *(short8*)&Pb[(rep * 32 + r) * 136 + c] =
                *(const short8*)&Q[(size_t)(q0 + rep * 32 + r) * 64 + c];
    }
    __syncthreads();
    // Q fragments (B-operand): rows qg*64 + w*16 + l15, qg in {0,1}
    short8 qf[2][2];
    #pragma unroll
    for (int qg = 0; qg < 2; ++qg)
        #pragma unroll
        for (int kk = 0; kk < 2; ++kk)
            qf[qg][kk] = *(const short8*)
                &Pb[(qg * 64 + w * 16 + l15) * 136 + kk * 32 + quad * 8];

    floatx4 acc[2][4];
    #pragma unroll
    for (int qg = 0; qg < 2; ++qg)
        #pragma unroll
        for (int dt = 0; dt < 4; ++dt) acc[qg][dt] = floatx4{0.f, 0.f, 0.f, 0.f};
    float l_part[2] = {0.f, 0.f};

    // staging coords: K thread owns (row, 32-col half); V thread owns
    // (kv pair, 16-d slab)
    const int kr = t & 127, kc = (t >> 7) * 32;
    const int vkv = (t & 63) * 2, vd = (t >> 6) * 16;

    // preload tile 0 into regs (K: 4 x short8 = full 32-col span)
    short8 kR[4], vR[4];
    #pragma unroll
    for (int c = 0; c < 4; ++c)
        kR[c] = *(const short8*)&K[(size_t)kr * 64 + kc + c * 8];
    vR[0] = *(const short8*)&V[(size_t)vkv * 64 + vd];
    vR[1] = *(const short8*)&V[(size_t)vkv * 64 + vd + 8];
    vR[2] = *(const short8*)&V[(size_t)(vkv + 1) * 64 + vd];
    vR[3] = *(const short8*)&V[(size_t)(vkv + 1) * 64 + vd + 8];

    for (int kt = 0; kt < N_; kt += 128) {
        __syncthreads();   // prior tile's LDS reads complete
        // regs -> LDS
        #pragma unroll
        for (int c = 0; c < 4; ++c)
            *(short8*)&Ks[kr * 72 + kc + c * 8] = kR[c];
        #pragma unroll
        for (int j = 0; j < 8; ++j) {
            unsigned int p0 = (unsigned int)(unsigned short)vR[0][j] |
                              ((unsigned int)(unsigned short)vR[2][j] << 16);
            unsigned int p1 = (unsigned int)(unsigned short)vR[1][j] |
                              ((unsigned int)(unsigned short)vR[3][j] << 16);
            *(unsigned int*)&Vt[(vd + j) * 136 + vkv]     = p0;
            *(unsigned int*)&Vt[(vd + 8 + j) * 136 + vkv] = p1;
        }
        __syncthreads();
        // prefetch next tile into regs — latency overlaps compute below
        if (kt + 128 < N_) {
            const int kt2 = kt + 128;
            #pragma unroll
            for (int c = 0; c < 4; ++c)
                kR[c] = *(const short8*)&K[(size_t)(kt2 + kr) * 64 + kc + c * 8];
            vR[0] = *(const short8*)&V[(size_t)(kt2 + vkv) * 64 + vd];
            vR[1] = *(const short8*)&V[(size_t)(kt2 + vkv) * 64 + vd + 8];
            vR[2] = *(const short8*)&V[(size_t)(kt2 + vkv + 1) * 64 + vd];
            vR[3] = *(const short8*)&V[(size_t)(kt2 + vkv + 1) * 64 + vd + 8];
        }

        // S^T = K . Q^T : 8 kv-tiles of 16; each A-frag feeds both q-groups
        floatx4 sc[2][8];
        #pragma unroll
        for (int ct = 0; ct < 8; ++ct) {
            short8 a0 = *(const short8*)&Ks[(ct * 16 + l15) * 72 + quad * 8];
            short8 a1 = *(const short8*)&Ks[(ct * 16 + l15) * 72 + 32 + quad * 8];
            #pragma unroll
            for (int qg = 0; qg < 2; ++qg) {
                floatx4 r = {0.f, 0.f, 0.f, 0.f};
                r = __builtin_amdgcn_mfma_f32_16x16x32_bf16(a0, qf[qg][0], r, 0, 0, 0);
                r = __builtin_amdgcn_mfma_f32_16x16x32_bf16(a1, qf[qg][1], r, 0, 0, 0);
                sc[qg][ct] = r;
            }
        }

        // fixed-reference softmax: p = exp2(s), defer the sum
        #pragma unroll
        for (int qg = 0; qg < 2; ++qg) {
            const int prow = qg * 64 + w * 16 + l15;
            #pragma unroll
            for (int ct = 0; ct < 8; ++ct) {
                float p0 = __builtin_amdgcn_exp2f(sc[qg][ct][0]);
                float p1 = __builtin_amdgcn_exp2f(sc[qg][ct][1]);
                float p2 = __builtin_amdgcn_exp2f(sc[qg][ct][2]);
                float p3 = __builtin_amdgcn_exp2f(sc[qg][ct][3]);
                l_part[qg] += (p0 + p1) + (p2 + p3);
                uint2 pk;
                pk.x = pk2bf(p0, p1);
                pk.y = pk2bf(p2, p3);
                *(uint2*)&Pb[prow * 136 + ct * 16 + quad * 4] = pk;
            }
        }
        asm volatile("" ::: "memory");

        // O^T += V^T . P : Vt A-frags shared across both q-groups
        #pragma unroll
        for (int kk = 0; kk < 4; ++kk) {
            short8 pbf[2];
            #pragma unroll
            for (int qg = 0; qg < 2; ++qg)
                pbf[qg] = *(const short8*)
                    &Pb[(qg * 64 + w * 16 + l15) * 136 + kk * 32 + quad * 8];
            #pragma unroll
            for (int dt = 0; dt < 4; ++dt) {
                short8 va = *(const short8*)
                    &Vt[(dt * 16 + l15) * 136 + kk * 32 + quad * 8];
                #pragma unroll
                for (int qg = 0; qg < 2; ++qg)
                    acc[qg][dt] = __builtin_amdgcn_mfma_f32_16x16x32_bf16(
                        va, pbf[qg], acc[qg][dt], 0, 0, 0);
            }
        }
    }

    // denominators + epilogue: O^T regs -> Pb[q][d], then coalesced copy-out
    asm volatile("" ::: "memory");
    #pragma unroll
    for (int qg = 0; qg < 2; ++qg) {
        l_part[qg] += __shfl_xor(l_part[qg], 16);
        l_part[qg] += __shfl_xor(l_part[qg], 32);
        const float inv = 1.0f / l_part[qg];
        const int orow = qg * 64 + w * 16 + l15;
        #pragma unroll
        for (int dt = 0; dt < 4; ++dt) {
            uint2 o2;
            o2.x = pk2bf(acc[qg][dt][0] * inv, acc[qg][dt][1] * inv);
            o2.y = pk2bf(acc[qg][dt][2] * inv, acc[qg][dt][3] * inv);
            *(uint2*)&Pb[orow * 136 + dt * 16 + quad * 4] = o2;
        }
    }
    __syncthreads();
    const int bidx = bh >> 4, h = bh & 15;
    {
        const int r = t >> 3, c = (t & 7) * 8;
        #pragma unroll
        for (int rep = 0; rep < 4; ++rep) {
            const int row = rep * 32 + r;
            *(short8*)&ob[((size_t)(bidx * N_ + q0 + row)) * C_ + h * 64 + c] =
                *(const short8*)&Pb[row * 136 + c];
        }
    }
}

// ---------------------------------------------------------------------------
extern "C" void kernel_launch(void* const* d_in, const int* in_sizes, int n_in,
                              void* d_out, int out_size, void* d_ws, size_t ws_size,
                              hipStream_t stream) {
    const float* x      = (const float*)d_in[0];
    const float* W_qkv  = (const float*)d_in[1];
    const float* qn_w   = (const float*)d_in[2];
    const float* qn_b   = (const float*)d_in[3];
    const float* kn_w   = (const float*)d_in[4];
    const float* kn_b   = (const float*)d_in[5];
    const float* W_proj = (const float*)d_in[6];
    const float* b_proj = (const float*)d_in[7];
    float* out = (float*)d_out;

    unsigned short* qb  = (unsigned short*)d_ws;               // 3 x QSZ bf16
    unsigned short* kb  = qb + (size_t)QSZ;
    unsigned short* vb  = kb + (size_t)QSZ;
    unsigned short* ob  = vb + (size_t)QSZ;                    // [B,N,C] bf16
    unsigned short* xb  = ob + (size_t)B_ * N_ * C_;           // [4096][1024]
    unsigned short* wqt = xb + (size_t)B_ * N_ * C_;           // [3072][1024]
    unsigned short* wpt = wqt + (size_t)3 * C_ * C_;           // [1024][1024]

    pack_bf16_kernel<<<dim3((B_ * N_ * C_) / 1024), 256, 0, stream>>>(x, xb);
    transpose_pack2_kernel<<<dim3(128, 32), 256, 0, stream>>>(W_qkv, wqt, W_proj, wpt);
    gemm_qkv_kernel<<<dim3(24, 32), 256, 0, stream>>>(
        xb, wqt, qn_w, qn_b, kn_w, kn_b, qb, kb, vb);
    flash_kernel<<<dim3(N_ / 128, B_ * H_), 256, 0, stream>>>(qb, kb, vb, ob);
    gemm_proj_kernel<<<dim3(8, 64), 256, 0, stream>>>(ob, wpt, b_proj, out);
}